// Round 1
// 601.108 us; speedup vs baseline: 1.6347x; 1.6347x over previous
//
#include <hip/hip_runtime.h>

// TransformerEncoder on MI355X (gfx950). fp32 I/O, bf16 MFMA compute.
// B=2, S=2048, E=1024, H=16, A=64, FF=4096. Tokens M = 4096.
//
// All GEMM operands pre-converted to bf16 once; GEMMs use
// global_load_lds(16B) + XOR-swizzled LDS (T2) + 128-wide tiles (m97 class).
// FFN algebra: ff = relu(mha@W12 + b12), W12 = W1@W2 (bf16, computed on device).
//
// Workspace (ws >= 20MB+4KB, same budget as verified predecessor):
//   phase0: [0,8M)=W1b bf16, [8M,16M)=W2t bf16          (W12 gemm inputs)
//   phase1: [0,6M)=WBt bf16 (fused Wq|Wk|Wv, [n][k]), [8M,16M)=xb bf16
//   phase2: [0,8M)=attnB bf16 (flash out, token-major)  (proj A)
//   phase3: [0,16M)=res2 fp32
//   fixed : [16M,18M)=WprojT bf16, [18M,20M)=W12T bf16, [20M,+4K)=b12 f32
// d_out: enc slot = Q (fp32 head-major) -> res1/mha -> encoded; K/V final.
//
// MFMA 16x16x32 bf16 layouts (harness-verified in predecessor):
//   A[m][k]: m=lane&15, k=(lane>>4)*8+j ; B[k][n]: n=lane&15, same k
//   C/D: col=lane&15, row=(lane>>4)*4+reg

typedef unsigned short u16;
typedef unsigned int u32;
typedef __bf16 bf16x8 __attribute__((ext_vector_type(8)));
typedef float f32x4 __attribute__((ext_vector_type(4)));

#define AS1 __attribute__((address_space(1)))
#define AS3 __attribute__((address_space(3)))

__device__ __forceinline__ u16 f2bf(float f) {
    u32 x = __float_as_uint(f);
    x += 0x7fffu + ((x >> 16) & 1u);
    return (u16)(x >> 16);
}

// XOR swizzle key for a 128B LDS row: spreads 16-lane row-strided b128 reads
// across 8 bank groups AND keeps column-scatter u16/u8 writes ~2-way.
__device__ __forceinline__ int swz(int row) { return ((row ^ (row >> 2)) & 7) << 4; }

// async global->LDS, 16B per lane. LDS dest is wave-uniform base + lane*16
// (linear); swizzle is applied by pre-swizzling the per-lane GLOBAL source.
__device__ __forceinline__ void gload16(void* lds, const void* g) {
    __builtin_amdgcn_global_load_lds((const AS1 void*)(unsigned long long)g,
                                     (AS3 void*)(u32)(unsigned long long)lds, 16, 0, 0);
}

// ---------------------------------------------------------------- GEMM
// C[m,n] = sum_k A[m,k] * B[n,k]^T.  B always bf16 [n][k] (pre-transposed).
// AF32=0: A bf16 [m][k] via global_load_lds. AF32=1: A fp32 [m][K], convert-stage.
// OMODE 0: fp32 out (+bias/relu/resid/resid2), ldc=1024
// OMODE 1: QKV routing -> head-major fp32 (n = sel*1024 + h*64 + a)
// OMODE 2: bf16 transposed out Ct[n][m]  (produces W12T)
template <int BM, int AF32, int OMODE>
__launch_bounds__(256, 3)
__global__ void k_mm(const u16* Ab, const float* Af, const u16* __restrict__ Bt, int K,
                     float* C, u16* Ct, const float* __restrict__ bias,
                     const float* resid, const float* resid2,
                     float* oQ, float* oK, float* oV, int relu) {
    constexpr int MF = BM / 32;
    __shared__ __align__(16) u16 As[BM * 64];
    __shared__ __align__(16) u16 Bs[128 * 64];
    const int tid = threadIdx.x;
    const int wave = tid >> 6, lane = tid & 63, quad = lane >> 4, l16 = lane & 15;
    const int wm = wave & 1, wn = wave >> 1;
    const int m0 = blockIdx.x * BM, n0 = blockIdx.y * 128;

    f32x4 acc[MF][4];
#pragma unroll
    for (int mf = 0; mf < MF; ++mf)
#pragma unroll
        for (int nf = 0; nf < 4; ++nf) acc[mf][nf] = (f32x4){0.f, 0.f, 0.f, 0.f};

    for (int kk = 0; kk < K; kk += 64) {
        // ---- stage A tile [BM][64]
        if constexpr (AF32 == 0) {
#pragma unroll
            for (int i = 0; i < BM / 32; ++i) {
                const int chunk = wave * (BM / 32) + i;      // 8 rows / chunk
                const int row = chunk * 8 + (lane >> 3);
                const int cb = (lane & 7) * 16;              // dest byte in row
                gload16((char*)As + chunk * 1024,
                        Ab + (long long)(m0 + row) * K + kk + ((cb ^ swz(row)) >> 1));
            }
        } else {
#pragma unroll
            for (int i = 0; i < BM / 16; ++i) {
                const int slot = tid + i * 256;
                const int row = slot >> 4, c4 = (slot & 15) * 4;
                float4 v = *(const float4*)(Af + (long long)(m0 + row) * K + kk + c4);
                ushort4 s;
                s.x = f2bf(v.x); s.y = f2bf(v.y); s.z = f2bf(v.z); s.w = f2bf(v.w);
                *(ushort4*)((char*)As + row * 128 + ((c4 * 2) ^ swz(row))) = s;
            }
        }
        // ---- stage B tile [128][64]
#pragma unroll
        for (int i = 0; i < 4; ++i) {
            const int chunk = wave * 4 + i;
            const int row = chunk * 8 + (lane >> 3);
            const int cb = (lane & 7) * 16;
            gload16((char*)Bs + chunk * 1024,
                    Bt + (long long)(n0 + row) * K + kk + ((cb ^ swz(row)) >> 1));
        }
        __syncthreads();   // compiler drains vmcnt/lgkm before barrier
        // ---- compute
#pragma unroll
        for (int ks = 0; ks < 2; ++ks) {
            bf16x8 af[MF], bfr[4];
#pragma unroll
            for (int mf = 0; mf < MF; ++mf) {
                const int row = wm * (BM / 2) + mf * 16 + l16;
                af[mf] = *(const bf16x8*)((const char*)As + row * 128 +
                                          ((ks * 64 + quad * 16) ^ swz(row)));
            }
#pragma unroll
            for (int nf = 0; nf < 4; ++nf) {
                const int row = wn * 64 + nf * 16 + l16;
                bfr[nf] = *(const bf16x8*)((const char*)Bs + row * 128 +
                                           ((ks * 64 + quad * 16) ^ swz(row)));
            }
#pragma unroll
            for (int mf = 0; mf < MF; ++mf)
#pragma unroll
                for (int nf = 0; nf < 4; ++nf)
                    acc[mf][nf] = __builtin_amdgcn_mfma_f32_16x16x32_bf16(af[mf], bfr[nf],
                                                                          acc[mf][nf], 0, 0, 0);
        }
        __syncthreads();
    }

    // ---- epilogue
#pragma unroll
    for (int mf = 0; mf < MF; ++mf) {
#pragma unroll
        for (int nf = 0; nf < 4; ++nf) {
#pragma unroll
            for (int r = 0; r < 4; ++r) {
                const int row = m0 + wm * (BM / 2) + mf * 16 + quad * 4 + r;
                const int col = n0 + wn * 64 + nf * 16 + l16;
                float v = acc[mf][nf][r];
                if constexpr (OMODE == 0) {
                    if (bias) v += bias[col];
                    if (relu) v = fmaxf(v, 0.f);
                    if (resid) v += resid[(long long)row * 1024 + col];
                    if (resid2) v += resid2[(long long)row * 1024 + col];
                    C[(long long)row * 1024 + col] = v;
                } else if constexpr (OMODE == 1) {
                    const int sel = col >> 10, h = (col >> 6) & 15, a = col & 63;
                    float* dst = (sel == 0) ? oQ : ((sel == 1) ? oK : oV);
                    dst[(long long)h * 262144 + (long long)row * 64 + a] = v;
                } else {
                    Ct[(long long)col * 1024 + row] = f2bf(v);
                }
            }
        }
    }
}

// ---------------------------------------------------------------- converts
// out bf16 = in1 (+ in2), linear. 1024 elems/block.
__global__ void k_cvtx(const float* __restrict__ a, const float* __restrict__ b,
                       u16* __restrict__ o) {
    const long long i = ((long long)blockIdx.x * 256 + threadIdx.x) * 4;
    float4 v = *(const float4*)(a + i);
    if (b) {
        float4 u = *(const float4*)(b + i);
        v.x += u.x; v.y += u.y; v.z += u.z; v.w += u.w;
    }
    ushort4 s;
    s.x = f2bf(v.x); s.y = f2bf(v.y); s.z = f2bf(v.z); s.w = f2bf(v.w);
    *(ushort4*)(o + i) = s;
}

// transpose-convert to bf16 [n][k]. headmode: in = W[h][k][a] (n = h*64+a, K=1024);
// else in = W[k][n] with row stride ldn.
__global__ void k_cvtt(const float* __restrict__ in, u16* __restrict__ out,
                       int K, int ldn, int headmode) {
    const int n = blockIdx.x;
    const int tid = threadIdx.x;
    long long base;
    int stride;
    if (headmode) { base = (long long)(n >> 6) * 65536 + (n & 63); stride = 64; }
    else          { base = n;                                      stride = ldn; }
    for (int k = tid; k < K; k += 256)
        out[(long long)n * K + k] = f2bf(in[base + (long long)k * stride]);
}

// ---------------------------------------------------------------- b12 = b1@W2 + b2
__global__ void k_b12(const float* __restrict__ b1, const float* __restrict__ W2,
                      const float* __restrict__ b2, float* __restrict__ b12) {
    __shared__ float red[256];
    const int tid = threadIdx.x;
    const int o = blockIdx.x * 16 + (tid & 15);
    const int fc = tid >> 4;                       // 16 chunks x 256 f
    float s = 0.f;
    for (int f = fc * 256; f < fc * 256 + 256; ++f) s += b1[f] * W2[(long long)f * 1024 + o];
    red[tid] = s;
    __syncthreads();
    if (tid < 16) {
        float t = 0.f;
#pragma unroll
        for (int c = 0; c < 16; ++c) t += red[c * 16 + tid];
        b12[blockIdx.x * 16 + tid] = t + b2[blockIdx.x * 16 + tid];
    }
}

// ---------------------------------------------------------------- flash attention
// grid (32, H*B). Block: 64 q-rows (wave w owns rows w*16..+15), KV tiles of 64.
// scale = 1/sqrt(E) = 1/32, causal, online softmax. Output bf16 token-major
// attnB[tok][h*64+a]. blockIdx.x reversed so long (late-q) blocks launch first.
__launch_bounds__(256, 4)
__global__ void k_flash(const float* __restrict__ Qa, const float* __restrict__ Kg,
                        const float* __restrict__ Vg, u16* __restrict__ Ob) {
    __shared__ __align__(16) u16 Qs[64 * 72];
    __shared__ __align__(16) u16 Ks[64 * 72];
    __shared__ __align__(16) u16 Vt[64 * 64];     // Vt[a][kv], XOR-swizzled rows
    __shared__ __align__(16) u16 Pb[4 * 16 * 72];
    const int tid = threadIdx.x;
    const int wave = tid >> 6, lane = tid & 63, quad = lane >> 4, l16 = lane & 15;
    const int hb = blockIdx.y, h = hb >> 1, b = hb & 1;
    const int xr = (int)gridDim.x - 1 - (int)blockIdx.x;
    const int q0 = xr * 64;
    const long long base = (long long)h * 262144 + (long long)b * 131072;
    const float* Qp = Qa + base + (long long)q0 * 64;
    const float* Kp = Kg + base;
    const float* Vp = Vg + base;
    const float NEG = -1.0e30f;

    // stage Q tile [64][64] fp32 -> bf16 (pad-72 rows: reads 2-way, free)
#pragma unroll
    for (int i = 0; i < 4; ++i) {
        const int slot = tid + i * 256;
        const int row = slot >> 4, c4 = (slot & 15) * 4;
        float4 v = *(const float4*)(Qp + row * 64 + c4);
        ushort4 s;
        s.x = f2bf(v.x); s.y = f2bf(v.y); s.z = f2bf(v.z); s.w = f2bf(v.w);
        *(ushort4*)&Qs[row * 72 + c4] = s;
    }
    __syncthreads();
    const bf16x8 aq0 = *(const bf16x8*)&Qs[(wave * 16 + l16) * 72 + quad * 8];
    const bf16x8 aq1 = *(const bf16x8*)&Qs[(wave * 16 + l16) * 72 + 32 + quad * 8];

    f32x4 o[4];
#pragma unroll
    for (int g = 0; g < 4; ++g) o[g] = (f32x4){0.f, 0.f, 0.f, 0.f};
    float mrow[4] = {NEG, NEG, NEG, NEG};
    float lrow[4] = {0.f, 0.f, 0.f, 0.f};
    u16* Pw = Pb + wave * 16 * 72;

    const int nit = xr + 1;
    for (int it = 0; it < nit; ++it) {
        const int k0 = it * 64;
        __syncthreads();                           // prev PV reads done
        // stage K [64][64] (pad-72) and V -> Vt[a][kv] swizzled
#pragma unroll
        for (int i = 0; i < 4; ++i) {
            const int slot = tid + i * 256;
            const int row = slot >> 4, c4 = (slot & 15) * 4;   // row = kv
            float4 kv4 = *(const float4*)(Kp + (long long)(k0 + row) * 64 + c4);
            ushort4 s;
            s.x = f2bf(kv4.x); s.y = f2bf(kv4.y); s.z = f2bf(kv4.z); s.w = f2bf(kv4.w);
            *(ushort4*)&Ks[row * 72 + c4] = s;
            float4 vv = *(const float4*)(Vp + (long long)(k0 + row) * 64 + c4);
            const int r2 = row * 2;
            *(u16*)((char*)Vt + (c4 + 0) * 128 + (r2 ^ swz(c4 + 0))) = f2bf(vv.x);
            *(u16*)((char*)Vt + (c4 + 1) * 128 + (r2 ^ swz(c4 + 1))) = f2bf(vv.y);
            *(u16*)((char*)Vt + (c4 + 2) * 128 + (r2 ^ swz(c4 + 2))) = f2bf(vv.z);
            *(u16*)((char*)Vt + (c4 + 3) * 128 + (r2 ^ swz(c4 + 3))) = f2bf(vv.w);
        }
        __syncthreads();
        // scores S[16q][64kv]
        f32x4 sc[4];
#pragma unroll
        for (int kg = 0; kg < 4; ++kg) {
            sc[kg] = (f32x4){0.f, 0.f, 0.f, 0.f};
            const bf16x8 bka = *(const bf16x8*)&Ks[(kg * 16 + l16) * 72 + quad * 8];
            const bf16x8 bkb = *(const bf16x8*)&Ks[(kg * 16 + l16) * 72 + 32 + quad * 8];
            sc[kg] = __builtin_amdgcn_mfma_f32_16x16x32_bf16(aq0, bka, sc[kg], 0, 0, 0);
            sc[kg] = __builtin_amdgcn_mfma_f32_16x16x32_bf16(aq1, bkb, sc[kg], 0, 0, 0);
        }
        const bool last = (it == nit - 1);         // only last tile crosses diagonal
        float ev[4][4];
#pragma unroll
        for (int r = 0; r < 4; ++r) {
            const int qg = q0 + wave * 16 + quad * 4 + r;
            float v0 = sc[0][r] * 0.03125f, v1 = sc[1][r] * 0.03125f;
            float v2 = sc[2][r] * 0.03125f, v3 = sc[3][r] * 0.03125f;
            if (last) {
                if (k0 + l16 > qg)      v0 = NEG;
                if (k0 + 16 + l16 > qg) v1 = NEG;
                if (k0 + 32 + l16 > qg) v2 = NEG;
                if (k0 + 48 + l16 > qg) v3 = NEG;
            }
            float tmax = fmaxf(fmaxf(v0, v1), fmaxf(v2, v3));
#pragma unroll
            for (int off = 1; off < 16; off <<= 1) tmax = fmaxf(tmax, __shfl_xor(tmax, off, 16));
            const float mo = mrow[r];
            const float mn = fmaxf(mo, tmax);
            const float alpha = __expf(mo - mn);
            const float e0 = __expf(v0 - mn), e1 = __expf(v1 - mn);
            const float e2 = __expf(v2 - mn), e3 = __expf(v3 - mn);
            float rs = (e0 + e1) + (e2 + e3);
#pragma unroll
            for (int off = 1; off < 16; off <<= 1) rs += __shfl_xor(rs, off, 16);
            lrow[r] = lrow[r] * alpha + rs;
            mrow[r] = mn;
            ev[0][r] = e0; ev[1][r] = e1; ev[2][r] = e2; ev[3][r] = e3;
#pragma unroll
            for (int g = 0; g < 4; ++g) o[g][r] *= alpha;
        }
        // P (C-layout) -> per-wave LDS -> A-layout
#pragma unroll
        for (int r = 0; r < 4; ++r)
#pragma unroll
            for (int kg = 0; kg < 4; ++kg)
                Pw[(quad * 4 + r) * 72 + kg * 16 + l16] = f2bf(ev[kg][r]);
        __syncthreads();
        const bf16x8 ap0 = *(const bf16x8*)&Pw[l16 * 72 + quad * 8];
        const bf16x8 ap1 = *(const bf16x8*)&Pw[l16 * 72 + 32 + quad * 8];
#pragma unroll
        for (int g = 0; g < 4; ++g) {
            const int ar = g * 16 + l16;
            const bf16x8 bv0 = *(const bf16x8*)((char*)Vt + ar * 128 + ((quad * 16) ^ swz(ar)));
            const bf16x8 bv1 = *(const bf16x8*)((char*)Vt + ar * 128 + ((64 + quad * 16) ^ swz(ar)));
            o[g] = __builtin_amdgcn_mfma_f32_16x16x32_bf16(ap0, bv0, o[g], 0, 0, 0);
            o[g] = __builtin_amdgcn_mfma_f32_16x16x32_bf16(ap1, bv1, o[g], 0, 0, 0);
        }
    }

    // epilogue: O /= l, bf16 token-major write
    const long long mb = (long long)b * 2048 + q0;
#pragma unroll
    for (int r = 0; r < 4; ++r) {
        const float inv = 1.0f / lrow[r];
        const long long m = mb + wave * 16 + quad * 4 + r;
#pragma unroll
        for (int g = 0; g < 4; ++g)
            Ob[m * 1024 + h * 64 + g * 16 + l16] = f2bf(o[g][r] * inv);
    }
}

// ---------------------------------------------------------------- layernorm (row of 1024)
__global__ void k_ln(const float* in1, const float* in2,
                     const float* __restrict__ g, const float* __restrict__ be,
                     float* out) {
    __shared__ float red[8];
    const int m = blockIdx.x;
    const int tid = threadIdx.x;
    const int e0 = tid * 4;
    const long long bp = (long long)m * 1024;
    float4 v = *(const float4*)(in1 + bp + e0);
    if (in2) {
        float4 u = *(const float4*)(in2 + bp + e0);
        v.x += u.x; v.y += u.y; v.z += u.z; v.w += u.w;
    }
    float s1 = v.x + v.y + v.z + v.w;
    float s2 = v.x * v.x + v.y * v.y + v.z * v.z + v.w * v.w;
#pragma unroll
    for (int off = 1; off < 64; off <<= 1) {
        s1 += __shfl_xor(s1, off);
        s2 += __shfl_xor(s2, off);
    }
    if ((tid & 63) == 0) {
        red[tid >> 6] = s1;
        red[4 + (tid >> 6)] = s2;
    }
    __syncthreads();
    const float S1 = red[0] + red[1] + red[2] + red[3];
    const float S2 = red[4] + red[5] + red[6] + red[7];
    const float mean = S1 * (1.0f / 1024.0f);
    const float var = S2 * (1.0f / 1024.0f) - mean * mean;
    const float rstd = rsqrtf(var + 1e-5f);
    float4 ug = *(const float4*)(g + e0);
    float4 ub = *(const float4*)(be + e0);
    float4 o;
    o.x = (v.x - mean) * rstd * ug.x + ub.x;
    o.y = (v.y - mean) * rstd * ug.y + ub.y;
    o.z = (v.z - mean) * rstd * ug.z + ub.z;
    o.w = (v.w - mean) * rstd * ug.w + ub.w;
    *(float4*)(out + bp + e0) = o;
}

// ---------------------------------------------------------------- launch
extern "C" void kernel_launch(void* const* d_in, const int* in_sizes, int n_in,
                              void* d_out, int out_size, void* d_ws, size_t ws_size,
                              hipStream_t stream) {
    (void)in_sizes; (void)n_in; (void)out_size; (void)ws_size;
    const float* emb    = (const float*)d_in[0];
    const float* pos    = (const float*)d_in[1];
    const float* Wq     = (const float*)d_in[2];
    const float* Wk     = (const float*)d_in[3];
    const float* Wv     = (const float*)d_in[4];
    const float* Wproj  = (const float*)d_in[5];
    const float* W1     = (const float*)d_in[6];
    const float* b1     = (const float*)d_in[7];
    const float* W2     = (const float*)d_in[8];
    const float* b2     = (const float*)d_in[9];
    const float* g_attn = (const float*)d_in[10];
    const float* be_attn= (const float*)d_in[11];
    const float* g_ffn  = (const float*)d_in[12];
    const float* be_ffn = (const float*)d_in[13];
    const float* g_out  = (const float*)d_in[14];
    const float* be_out = (const float*)d_in[15];

    float* enc   = (float*)d_out;          // Q -> res1/mha -> encoded
    float* out_K = enc + 4194304;
    float* out_V = enc + 8388608;

    u16* wsu    = (u16*)d_ws;
    u16* W1b    = wsu;                     // [0,8MB)   phase0
    u16* W2t    = wsu + 4194304;           // [8,16MB)  phase0
    u16* WBt    = wsu;                     // [0,6MB)   phase1
    u16* xb     = wsu + 4194304;           // [8,16MB)  phase1
    u16* attnB  = wsu;                     // [0,8MB)   phase2
    u16* WpT    = wsu + 8388608;           // [16,18MB)
    u16* W12T   = wsu + 9437184;           // [18,20MB)
    float* b12  = (float*)(wsu + 10485760);// [20MB,+4KB)
    float* res2 = (float*)d_ws;            // [0,16MB)  phase3

    // phase0: W12T = (W1@W2)^T in bf16
    k_cvtx<<<4096, 256, 0, stream>>>(W1, nullptr, W1b);
    k_cvtt<<<1024, 256, 0, stream>>>(W2, W2t, 4096, 1024, 0);
    k_mm<64, 0, 2><<<dim3(16, 8), 256, 0, stream>>>(W1b, nullptr, W2t, 4096,
        nullptr, W12T, nullptr, nullptr, nullptr, nullptr, nullptr, nullptr, 0);
    k_b12<<<64, 256, 0, stream>>>(b1, W2, b2, b12);

    // phase1: bf16 operands for fused QKV
    k_cvtx<<<4096, 256, 0, stream>>>(emb, pos, xb);
    k_cvtt<<<1024, 256, 0, stream>>>(Wq, WBt,           1024, 64, 1);
    k_cvtt<<<1024, 256, 0, stream>>>(Wk, WBt + 1048576, 1024, 64, 1);
    k_cvtt<<<1024, 256, 0, stream>>>(Wv, WBt + 2097152, 1024, 64, 1);
    k_cvtt<<<1024, 256, 0, stream>>>(Wproj, WpT,        1024, 1024, 0);

    // fused QKV: [4096 x 3072] = xb @ [Wq|Wk|Wv], head-major fp32 outputs
    k_mm<128, 0, 1><<<dim3(32, 24), 256, 0, stream>>>(xb, nullptr, WBt, 1024,
        nullptr, nullptr, nullptr, nullptr, nullptr, enc, out_K, out_V, 0);

    // phase2: flash attention -> attnB bf16
    k_flash<<<dim3(32, 32), 256, 0, stream>>>(enc, out_K, out_V, attnB);

    // res1 = attnB @ WprojT^T + emb + pos  -> enc
    k_mm<64, 0, 0><<<dim3(64, 8), 256, 0, stream>>>(attnB, nullptr, WpT, 1024,
        enc, nullptr, nullptr, emb, pos, nullptr, nullptr, nullptr, 0);
    k_ln<<<4096, 256, 0, stream>>>(enc, nullptr, g_attn, be_attn, enc);   // mha in-place

    // phase3: res2 = relu(mha @ W12 + b12) + mha -> ws
    k_mm<64, 1, 0><<<dim3(64, 8), 256, 0, stream>>>(nullptr, enc, W12T, 1024,
        res2, nullptr, b12, enc, nullptr, nullptr, nullptr, nullptr, 1);
    k_ln<<<4096, 256, 0, stream>>>(res2, nullptr, g_ffn, be_ffn, res2);   // ffout in-place
    k_ln<<<4096, 256, 0, stream>>>(res2, enc, g_out, be_out, enc);        // encoded
}

// Round 2
// 509.628 us; speedup vs baseline: 1.9281x; 1.1795x over previous
//
#include <hip/hip_runtime.h>

// TransformerEncoder on MI355X (gfx950). fp32 I/O, bf16 MFMA compute.
// B=2, S=2048, E=1024, H=16, A=64, FF=4096. Tokens M = 4096.
//
// ws layout (<= 20MB+4KB):
//   fixed : [16,18M)=WpT bf16, [18,20M)=W12T bf16, [20M,+4K)=b12 f32
//   phase0: [0,8M)=W1b bf16, [8,16M)=W2t bf16 (splitK partials in enc scratch)
//   phase1: [0,6M)=WBt bf16 (Wq|Wk|Wv [n][k]), [8,16M)=xb bf16
//   phase2: [0,8M)=VbT bf16 [hb][a][s]
//   phase3: [0,16M)=res1/mha fp32
// d_out: enc = {Qb bf16[0,8M) -> attnO bf16 in-place | Kb bf16[8,16M)}
//        -> (phase0 splitK scratch) -> res2 fp32 -> encoded fp32. K/V final fp32.

typedef unsigned short u16;
typedef unsigned int u32;
typedef __bf16 bf16x8 __attribute__((ext_vector_type(8)));
typedef float f32x4 __attribute__((ext_vector_type(4)));

#define AS1 __attribute__((address_space(1)))
#define AS3 __attribute__((address_space(3)))

__device__ __forceinline__ u16 f2bf(float f) {
    u32 x = __float_as_uint(f);
    x += 0x7fffu + ((x >> 16) & 1u);
    return (u16)(x >> 16);
}

// XOR swizzle key for a 128B LDS row (bits 4..6): 16-lane row-strided b128
// reads spread across 8 bank-groups (2-way = free).
__device__ __forceinline__ int swz(int row) { return ((row ^ (row >> 2)) & 7) << 4; }

// async global->LDS, 16B/lane. LDS dest = wave-uniform base + lane*16 (linear);
// swizzle applied by pre-swizzling the per-lane GLOBAL source (rule #21).
__device__ __forceinline__ void gload16(void* lds, const void* g) {
    __builtin_amdgcn_global_load_lds((const AS1 void*)(unsigned long long)g,
                                     (AS3 void*)(u32)(unsigned long long)lds, 16, 0, 0);
}

// ---------------------------------------------------------------- GEMM
// C[m,n] = sum_k A[m,k] * B[n,k]^T.  B bf16 [n][k].
// AMODE 0: A bf16 [m][K] via gload16.  1: A fp32 [m][K] convert-stage.
//       2: A = attnO bf16 head-major (addr = (k>>6)*262144 + m*64 + (k&63)).
// OMODE 0: fp32 out (+bias/relu/resid/resid2), ldc=1024.
//       1: QKV routing (Q->bf16 head-major, K->fp32+bf16, V->fp32).
//       2: fp32 transposed partial Cp[z][n][m]  (splitK for W12T).
template <int BM, int AMODE, int OMODE>
__launch_bounds__(256, 3)
__global__ void k_mm(const void* Ap, const u16* __restrict__ Bt, int K, int KZ,
                     float* C, float* Cp, const float* __restrict__ bias,
                     const float* resid, const float* resid2,
                     u16* oQb, float* oKf, u16* oKb, float* oVf, int relu) {
    constexpr int MF = BM / 32;
    __shared__ __align__(16) u16 As[BM * 64];
    __shared__ __align__(16) u16 Bs[128 * 64];
    const int tid = threadIdx.x;
    const int wave = tid >> 6, lane = tid & 63, quad = lane >> 4, l16 = lane & 15;
    const int wm = wave & 1, wn = wave >> 1;
    const int m0 = blockIdx.x * BM, n0 = blockIdx.y * 128;
    const int kbeg = blockIdx.z * KZ, kend = kbeg + KZ;

    f32x4 acc[MF][4];
#pragma unroll
    for (int mf = 0; mf < MF; ++mf)
#pragma unroll
        for (int nf = 0; nf < 4; ++nf) acc[mf][nf] = (f32x4){0.f, 0.f, 0.f, 0.f};

    for (int kk = kbeg; kk < kend; kk += 64) {
        __syncthreads();
        // ---- stage A [BM][64]
        if constexpr (AMODE == 1) {
            const float* Af = (const float*)Ap;
#pragma unroll
            for (int i = 0; i < BM / 16; ++i) {
                const int slot = tid + i * 256;
                const int row = slot >> 4, c4 = (slot & 15) * 4;
                float4 v = *(const float4*)(Af + (long long)(m0 + row) * K + kk + c4);
                ushort4 s;
                s.x = f2bf(v.x); s.y = f2bf(v.y); s.z = f2bf(v.z); s.w = f2bf(v.w);
                *(ushort4*)((char*)As + row * 128 + ((c4 * 2) ^ swz(row))) = s;
            }
        } else {
            const u16* Ab = (const u16*)Ap;
#pragma unroll
            for (int i = 0; i < BM / 32; ++i) {
                const int chunk = wave * (BM / 32) + i;
                const int row = chunk * 8 + (lane >> 3);
                const int cb = (lane & 7) * 16;
                const int e = kk + ((cb ^ swz(row)) >> 1);
                const u16* src;
                if constexpr (AMODE == 2)
                    src = Ab + (long long)(e >> 6) * 262144 + (long long)(m0 + row) * 64 + (e & 63);
                else
                    src = Ab + (long long)(m0 + row) * K + e;
                gload16((char*)As + chunk * 1024, src);
            }
        }
        // ---- stage B [128][64]
#pragma unroll
        for (int i = 0; i < 4; ++i) {
            const int chunk = wave * 4 + i;
            const int row = chunk * 8 + (lane >> 3);
            const int cb = (lane & 7) * 16;
            gload16((char*)Bs + chunk * 1024,
                    Bt + (long long)(n0 + row) * K + kk + ((cb ^ swz(row)) >> 1));
        }
        __syncthreads();
        // ---- compute
#pragma unroll
        for (int ks = 0; ks < 2; ++ks) {
            bf16x8 af[MF], bfr[4];
#pragma unroll
            for (int mf = 0; mf < MF; ++mf) {
                const int row = wm * (BM / 2) + mf * 16 + l16;
                af[mf] = *(const bf16x8*)((const char*)As + row * 128 +
                                          ((ks * 64 + quad * 16) ^ swz(row)));
            }
#pragma unroll
            for (int nf = 0; nf < 4; ++nf) {
                const int row = wn * 64 + nf * 16 + l16;
                bfr[nf] = *(const bf16x8*)((const char*)Bs + row * 128 +
                                           ((ks * 64 + quad * 16) ^ swz(row)));
            }
#pragma unroll
            for (int mf = 0; mf < MF; ++mf)
#pragma unroll
                for (int nf = 0; nf < 4; ++nf)
                    acc[mf][nf] = __builtin_amdgcn_mfma_f32_16x16x32_bf16(af[mf], bfr[nf],
                                                                          acc[mf][nf], 0, 0, 0);
        }
    }

    // ---- epilogue
#pragma unroll
    for (int mf = 0; mf < MF; ++mf) {
#pragma unroll
        for (int nf = 0; nf < 4; ++nf) {
#pragma unroll
            for (int r = 0; r < 4; ++r) {
                const long long row = m0 + wm * (BM / 2) + mf * 16 + quad * 4 + r;
                const int col = n0 + wn * 64 + nf * 16 + l16;
                float v = acc[mf][nf][r];
                if constexpr (OMODE == 0) {
                    if (bias) v += bias[col];
                    if (relu) v = fmaxf(v, 0.f);
                    if (resid) v += resid[row * 1024 + col];
                    if (resid2) v += resid2[row * 1024 + col];
                    C[row * 1024 + col] = v;
                } else if constexpr (OMODE == 1) {
                    const int sel = col >> 10, h = (col >> 6) & 15, a = col & 63;
                    const long long idx = (long long)h * 262144 + row * 64 + a;
                    if (sel == 0) oQb[idx] = f2bf(v);
                    else if (sel == 1) { oKf[idx] = v; oKb[idx] = f2bf(v); }
                    else oVf[idx] = v;
                } else {
                    Cp[(long long)blockIdx.z * 1048576 + (long long)col * 1024 + row] = v;
                }
            }
        }
    }
}

// ---------------------------------------------------------------- converts
// bf16 = in1 (+ in2), linear; 1024 elems/block.
__global__ void k_cvtx(const float* __restrict__ a, const float* __restrict__ b,
                       u16* __restrict__ o) {
    const long long i = ((long long)blockIdx.x * 256 + threadIdx.x) * 4;
    float4 v = *(const float4*)(a + i);
    if (b) {
        float4 u = *(const float4*)(b + i);
        v.x += u.x; v.y += u.y; v.z += u.z; v.w += u.w;
    }
    ushort4 s;
    s.x = f2bf(v.x); s.y = f2bf(v.y); s.z = f2bf(v.z); s.w = f2bf(v.w);
    *(ushort4*)(o + i) = s;
}

// tiled 64x64 transpose-convert: out[z*szout + c*ldout + (x*64+r)] =
// bf16(in[z*szin + (x*64+r)*ldin + c]). Coalesced both sides.
__global__ void k_tc(const float* __restrict__ in, u16* __restrict__ out,
                     long long ldin, long long ldout, long long szin, long long szout) {
    __shared__ float T[64][65];
    const int x = blockIdx.x, z = blockIdx.y, tid = threadIdx.x;
    const float* ip = in + (long long)z * szin + (long long)x * 64 * ldin;
    u16* op = out + (long long)z * szout + (long long)x * 64;
#pragma unroll
    for (int i = 0; i < 4; ++i) {
        const int slot = tid + i * 256;
        const int r = slot >> 4, c4 = (slot & 15) * 4;
        float4 v = *(const float4*)(ip + (long long)r * ldin + c4);
        T[r][c4] = v.x; T[r][c4 + 1] = v.y; T[r][c4 + 2] = v.z; T[r][c4 + 3] = v.w;
    }
    __syncthreads();
#pragma unroll
    for (int i = 0; i < 4; ++i) {
        const int slot = tid + i * 256;
        const int c = slot >> 4, r4 = (slot & 15) * 4;
        ushort4 s;
        s.x = f2bf(T[r4][c]); s.y = f2bf(T[r4 + 1][c]);
        s.z = f2bf(T[r4 + 2][c]); s.w = f2bf(T[r4 + 3][c]);
        *(ushort4*)(op + (long long)c * ldout + r4) = s;
    }
}

// QKV weight transpose: z -> (w = z>>4, h = z&15); in W[h][k][a] -> WBt[(w*1024+h*64+a)][k]
__global__ void k_tcq(const float* __restrict__ Wq, const float* __restrict__ Wk,
                      const float* __restrict__ Wv, u16* __restrict__ out) {
    __shared__ float T[64][65];
    const int x = blockIdx.x, z = blockIdx.y, tid = threadIdx.x;
    const int w = z >> 4, h = z & 15;
    const float* ip = (w == 0 ? Wq : (w == 1 ? Wk : Wv)) + h * 65536 + x * 64 * 64;
    u16* op = out + (long long)(w * 16 + h) * 65536 + x * 64;
#pragma unroll
    for (int i = 0; i < 4; ++i) {
        const int slot = tid + i * 256;
        const int r = slot >> 4, c4 = (slot & 15) * 4;
        float4 v = *(const float4*)(ip + r * 64 + c4);
        T[r][c4] = v.x; T[r][c4 + 1] = v.y; T[r][c4 + 2] = v.z; T[r][c4 + 3] = v.w;
    }
    __syncthreads();
#pragma unroll
    for (int i = 0; i < 4; ++i) {
        const int slot = tid + i * 256;
        const int c = slot >> 4, r4 = (slot & 15) * 4;
        ushort4 s;
        s.x = f2bf(T[r4][c]); s.y = f2bf(T[r4 + 1][c]);
        s.z = f2bf(T[r4 + 2][c]); s.w = f2bf(T[r4 + 3][c]);
        *(ushort4*)(op + (long long)c * 1024 + r4) = s;
    }
}

// splitK reduce: W12T = bf16(P0 + P1)
__global__ void k_red(const float* __restrict__ P, u16* __restrict__ out) {
    const long long i = ((long long)blockIdx.x * 256 + threadIdx.x) * 4;
    float4 a = *(const float4*)(P + i);
    float4 b = *(const float4*)(P + i + 1048576);
    ushort4 s;
    s.x = f2bf(a.x + b.x); s.y = f2bf(a.y + b.y);
    s.z = f2bf(a.z + b.z); s.w = f2bf(a.w + b.w);
    *(ushort4*)(out + i) = s;
}

// ---------------------------------------------------------------- b12 = b1@W2 + b2
__global__ void k_b12(const float* __restrict__ b1, const float* __restrict__ W2,
                      const float* __restrict__ b2, float* __restrict__ b12) {
    __shared__ float red[256];
    const int tid = threadIdx.x;
    const int o = blockIdx.x * 16 + (tid & 15);
    const int fc = tid >> 4;
    float s = 0.f;
    for (int f = fc * 256; f < fc * 256 + 256; ++f) s += b1[f] * W2[(long long)f * 1024 + o];
    red[tid] = s;
    __syncthreads();
    if (tid < 16) {
        float t = 0.f;
#pragma unroll
        for (int c = 0; c < 16; ++c) t += red[c * 16 + tid];
        b12[blockIdx.x * 16 + tid] = t + b2[blockIdx.x * 16 + tid];
    }
}

// ---------------------------------------------------------------- flash attention
// grid (32, H*B). 64 q-rows/block (wave w owns rows w*16..+15), KV tiles of 64,
// double-buffered DMA staging, ONE barrier per tile, prefetch hides load latency.
// Inputs bf16: Qb/Kb head-major [h][t][64], VbT [hb][a][s]. scale 1/32, causal.
// Output bf16 written IN-PLACE over this block's own Q tile (head-major).
__launch_bounds__(256, 3)
__global__ void k_flash(u16* Qb, const u16* __restrict__ Kb, const u16* __restrict__ Vg) {
    __shared__ __align__(16) u16 Ks[2][64 * 64];
    __shared__ __align__(16) u16 Vs[2][64 * 64];
    __shared__ __align__(16) u16 Pb[4 * 16 * 72];
    const int tid = threadIdx.x;
    const int wave = tid >> 6, lane = tid & 63, quad = lane >> 4, l16 = lane & 15;
    const int hb = blockIdx.y, h = hb >> 1, b = hb & 1;
    const int xr = 31 - (int)blockIdx.x;          // long blocks launch first
    const int q0 = xr * 64;
    const long long qbase = (long long)h * 262144 + (long long)b * 131072;
    u16* Qp = Qb + qbase + (long long)q0 * 64;
    const u16* Kp = Kb + qbase;
    const u16* Vp = Vg + (long long)hb * 131072;
    const float NEG = -1.0e30f;

    // Q -> registers (bf16, no LDS)
    const int qrow = wave * 16 + l16;
    const bf16x8 aq0 = *(const bf16x8*)(Qp + qrow * 64 + quad * 8);
    const bf16x8 aq1 = *(const bf16x8*)(Qp + qrow * 64 + 32 + quad * 8);

    f32x4 o[4];
#pragma unroll
    for (int g = 0; g < 4; ++g) o[g] = (f32x4){0.f, 0.f, 0.f, 0.f};
    float mrow[4] = {NEG, NEG, NEG, NEG};
    float lrow[4] = {0.f, 0.f, 0.f, 0.f};
    u16* Pw = Pb + wave * 16 * 72;

    auto stage = [&](int bi, int k0) {
#pragma unroll
        for (int i = 0; i < 2; ++i) {
            const int chunk = wave * 2 + i;
            const int row = chunk * 8 + (lane >> 3);
            const int cb = (lane & 7) * 16;
            const int eo = (cb ^ swz(row)) >> 1;
            gload16((char*)Ks[bi] + chunk * 1024, Kp + (long long)(k0 + row) * 64 + eo);
            gload16((char*)Vs[bi] + chunk * 1024, Vp + (long long)row * 2048 + k0 + eo);
        }
    };

    const int nit = xr + 1;
    stage(0, 0);
    int cur = 0;
    for (int it = 0; it < nit; ++it) {
        __syncthreads();                           // drains vmcnt(0): buf[cur] ready
        if (it + 1 < nit) stage(cur ^ 1, (it + 1) * 64);   // prefetch under compute
        // scores S[16q][64kv]
        f32x4 sc[4];
        __builtin_amdgcn_s_setprio(1);
#pragma unroll
        for (int kg = 0; kg < 4; ++kg) {
            const int krow = kg * 16 + l16;
            const bf16x8 bka = *(const bf16x8*)((const char*)Ks[cur] + krow * 128 +
                                                ((quad * 16) ^ swz(krow)));
            const bf16x8 bkb = *(const bf16x8*)((const char*)Ks[cur] + krow * 128 +
                                                ((64 + quad * 16) ^ swz(krow)));
            sc[kg] = (f32x4){0.f, 0.f, 0.f, 0.f};
            sc[kg] = __builtin_amdgcn_mfma_f32_16x16x32_bf16(aq0, bka, sc[kg], 0, 0, 0);
            sc[kg] = __builtin_amdgcn_mfma_f32_16x16x32_bf16(aq1, bkb, sc[kg], 0, 0, 0);
        }
        __builtin_amdgcn_s_setprio(0);
        const bool last = (it == nit - 1);         // only last tile crosses diagonal
        const int k0 = it * 64;
        float ev[4][4];
#pragma unroll
        for (int r = 0; r < 4; ++r) {
            const int qg = q0 + wave * 16 + quad * 4 + r;
            float v0 = sc[0][r] * 0.03125f, v1 = sc[1][r] * 0.03125f;
            float v2 = sc[2][r] * 0.03125f, v3 = sc[3][r] * 0.03125f;
            if (last) {
                if (k0 + l16 > qg)      v0 = NEG;
                if (k0 + 16 + l16 > qg) v1 = NEG;
                if (k0 + 32 + l16 > qg) v2 = NEG;
                if (k0 + 48 + l16 > qg) v3 = NEG;
            }
            float tmax = fmaxf(fmaxf(v0, v1), fmaxf(v2, v3));
#pragma unroll
            for (int off = 1; off < 16; off <<= 1) tmax = fmaxf(tmax, __shfl_xor(tmax, off, 16));
            const float mo = mrow[r];
            const float mn = fmaxf(mo, tmax);
            const float alpha = __expf(mo - mn);
            const float e0 = __expf(v0 - mn), e1 = __expf(v1 - mn);
            const float e2 = __expf(v2 - mn), e3 = __expf(v3 - mn);
            float rs = (e0 + e1) + (e2 + e3);
#pragma unroll
            for (int off = 1; off < 16; off <<= 1) rs += __shfl_xor(rs, off, 16);
            lrow[r] = lrow[r] * alpha + rs;
            mrow[r] = mn;
            ev[0][r] = e0; ev[1][r] = e1; ev[2][r] = e2; ev[3][r] = e3;
#pragma unroll
            for (int g = 0; g < 4; ++g) o[g][r] *= alpha;
        }
        // P (C-layout) -> per-wave LDS -> A-layout (no barrier: in-order DS per wave)
#pragma unroll
        for (int r = 0; r < 4; ++r)
#pragma unroll
            for (int kg = 0; kg < 4; ++kg)
                Pw[(quad * 4 + r) * 72 + kg * 16 + l16] = f2bf(ev[kg][r]);
        const bf16x8 ap0 = *(const bf16x8*)&Pw[l16 * 72 + quad * 8];
        const bf16x8 ap1 = *(const bf16x8*)&Pw[l16 * 72 + 32 + quad * 8];
        __builtin_amdgcn_s_setprio(1);
#pragma unroll
        for (int g = 0; g < 4; ++g) {
            const int ar = g * 16 + l16;
            const bf16x8 bv0 = *(const bf16x8*)((const char*)Vs[cur] + ar * 128 +
                                                ((quad * 16) ^ swz(ar)));
            const bf16x8 bv1 = *(const bf16x8*)((const char*)Vs[cur] + ar * 128 +
                                                ((64 + quad * 16) ^ swz(ar)));
            o[g] = __builtin_amdgcn_mfma_f32_16x16x32_bf16(ap0, bv0, o[g], 0, 0, 0);
            o[g] = __builtin_amdgcn_mfma_f32_16x16x32_bf16(ap1, bv1, o[g], 0, 0, 0);
        }
        __builtin_amdgcn_s_setprio(0);
        cur ^= 1;
    }

    // epilogue: O /= l, bf16 write in-place over own Q tile (head-major)
#pragma unroll
    for (int r = 0; r < 4; ++r) {
        const float inv = 1.0f / lrow[r];
        const int srow = wave * 16 + quad * 4 + r;
#pragma unroll
        for (int g = 0; g < 4; ++g)
            Qp[srow * 64 + g * 16 + l16] = f2bf(o[g][r] * inv);
    }
}

// ---------------------------------------------------------------- layernorm (row of 1024)
__global__ void k_ln(const float* in1, const float* in2,
                     const float* __restrict__ g, const float* __restrict__ be,
                     float* out) {
    __shared__ float red[8];
    const int m = blockIdx.x, tid = threadIdx.x, e0 = tid * 4;
    const long long bp = (long long)m * 1024;
    float4 v = *(const float4*)(in1 + bp + e0);
    if (in2) {
        float4 u = *(const float4*)(in2 + bp + e0);
        v.x += u.x; v.y += u.y; v.z += u.z; v.w += u.w;
    }
    float s1 = v.x + v.y + v.z + v.w;
    float s2 = v.x * v.x + v.y * v.y + v.z * v.z + v.w * v.w;
#pragma unroll
    for (int off = 1; off < 64; off <<= 1) { s1 += __shfl_xor(s1, off); s2 += __shfl_xor(s2, off); }
    if ((tid & 63) == 0) { red[tid >> 6] = s1; red[4 + (tid >> 6)] = s2; }
    __syncthreads();
    const float S1 = red[0] + red[1] + red[2] + red[3];
    const float S2 = red[4] + red[5] + red[6] + red[7];
    const float mean = S1 * (1.0f / 1024.0f);
    const float var = S2 * (1.0f / 1024.0f) - mean * mean;
    const float rstd = rsqrtf(var + 1e-5f);
    float4 ug = *(const float4*)(g + e0);
    float4 ub = *(const float4*)(be + e0);
    float4 o;
    o.x = (v.x - mean) * rstd * ug.x + ub.x;
    o.y = (v.y - mean) * rstd * ug.y + ub.y;
    o.z = (v.z - mean) * rstd * ug.z + ub.z;
    o.w = (v.w - mean) * rstd * ug.w + ub.w;
    *(float4*)(out + bp + e0) = o;
}

// fused: ffout = LN(res2)*g1+be1 ; out = LN(mha + ffout)*g2+be2
__global__ void k_ln23(const float* r2, const float* __restrict__ mha,
                       const float* __restrict__ g1, const float* __restrict__ be1,
                       const float* __restrict__ g2, const float* __restrict__ be2,
                       float* out) {
    __shared__ float red[8];
    const int m = blockIdx.x, tid = threadIdx.x, e0 = tid * 4;
    const long long bp = (long long)m * 1024;
    float4 v = *(const float4*)(r2 + bp + e0);
    float s1 = v.x + v.y + v.z + v.w;
    float s2 = v.x * v.x + v.y * v.y + v.z * v.z + v.w * v.w;
#pragma unroll
    for (int off = 1; off < 64; off <<= 1) { s1 += __shfl_xor(s1, off); s2 += __shfl_xor(s2, off); }
    if ((tid & 63) == 0) { red[tid >> 6] = s1; red[4 + (tid >> 6)] = s2; }
    __syncthreads();
    float S1 = red[0] + red[1] + red[2] + red[3];
    float S2 = red[4] + red[5] + red[6] + red[7];
    float mean = S1 * (1.0f / 1024.0f);
    float rstd = rsqrtf(S2 * (1.0f / 1024.0f) - mean * mean + 1e-5f);
    float4 ug = *(const float4*)(g1 + e0);
    float4 ub = *(const float4*)(be1 + e0);
    float4 vm = *(const float4*)(mha + bp + e0);
    float4 t;
    t.x = vm.x + (v.x - mean) * rstd * ug.x + ub.x;
    t.y = vm.y + (v.y - mean) * rstd * ug.y + ub.y;
    t.z = vm.z + (v.z - mean) * rstd * ug.z + ub.z;
    t.w = vm.w + (v.w - mean) * rstd * ug.w + ub.w;
    s1 = t.x + t.y + t.z + t.w;
    s2 = t.x * t.x + t.y * t.y + t.z * t.z + t.w * t.w;
#pragma unroll
    for (int off = 1; off < 64; off <<= 1) { s1 += __shfl_xor(s1, off); s2 += __shfl_xor(s2, off); }
    __syncthreads();
    if ((tid & 63) == 0) { red[tid >> 6] = s1; red[4 + (tid >> 6)] = s2; }
    __syncthreads();
    S1 = red[0] + red[1] + red[2] + red[3];
    S2 = red[4] + red[5] + red[6] + red[7];
    mean = S1 * (1.0f / 1024.0f);
    rstd = rsqrtf(S2 * (1.0f / 1024.0f) - mean * mean + 1e-5f);
    ug = *(const float4*)(g2 + e0);
    ub = *(const float4*)(be2 + e0);
    float4 oo;
    oo.x = (t.x - mean) * rstd * ug.x + ub.x;
    oo.y = (t.y - mean) * rstd * ug.y + ub.y;
    oo.z = (t.z - mean) * rstd * ug.z + ub.z;
    oo.w = (t.w - mean) * rstd * ug.w + ub.w;
    *(float4*)(out + bp + e0) = oo;
}

// ---------------------------------------------------------------- launch
extern "C" void kernel_launch(void* const* d_in, const int* in_sizes, int n_in,
                              void* d_out, int out_size, void* d_ws, size_t ws_size,
                              hipStream_t stream) {
    (void)in_sizes; (void)n_in; (void)out_size; (void)ws_size;
    const float* emb    = (const float*)d_in[0];
    const float* pos    = (const float*)d_in[1];
    const float* Wq     = (const float*)d_in[2];
    const float* Wk     = (const float*)d_in[3];
    const float* Wv     = (const float*)d_in[4];
    const float* Wproj  = (const float*)d_in[5];
    const float* W1     = (const float*)d_in[6];
    const float* b1     = (const float*)d_in[7];
    const float* W2     = (const float*)d_in[8];
    const float* b2     = (const float*)d_in[9];
    const float* g_attn = (const float*)d_in[10];
    const float* be_attn= (const float*)d_in[11];
    const float* g_ffn  = (const float*)d_in[12];
    const float* be_ffn = (const float*)d_in[13];
    const float* g_out  = (const float*)d_in[14];
    const float* be_out = (const float*)d_in[15];

    float* enc   = (float*)d_out;
    float* out_K = enc + 4194304;
    float* out_V = enc + 8388608;
    u16* QbU = (u16*)enc;                  // [0,8M) of enc: Qb -> attnO
    u16* KbU = (u16*)enc + 4194304;        // [8,16M) of enc: Kb

    u16* wsu    = (u16*)d_ws;
    u16* W1b    = wsu;                     // [0,8M)   phase0
    u16* W2t    = wsu + 4194304;           // [8,16M)  phase0
    u16* WBt    = wsu;                     // [0,6M)   phase1
    u16* xb     = wsu + 4194304;           // [8,16M)  phase1
    u16* VbT    = wsu;                     // [0,8M)   phase2
    u16* WpT    = wsu + 8388608;           // [16,18M)
    u16* W12T   = wsu + 9437184;           // [18,20M)
    float* b12  = (float*)(wsu + 10485760);// [20M,+4K)
    float* res1 = (float*)d_ws;            // [0,16M)  phase3 (mha after LN)

    // phase0: W12T = (W1@W2)^T bf16, splitK x2 (partials in enc scratch)
    k_cvtx<<<4096, 256, 0, stream>>>(W1, nullptr, W1b);
    k_tc<<<dim3(64, 16), 256, 0, stream>>>(W2, W2t, 1024, 4096, 64, 64 * 4096);
    k_mm<64, 0, 2><<<dim3(16, 8, 2), 256, 0, stream>>>(W1b, W2t, 4096, 2048,
        nullptr, enc, nullptr, nullptr, nullptr, nullptr, nullptr, nullptr, nullptr, 0);
    k_red<<<1024, 256, 0, stream>>>(enc, W12T);
    k_b12<<<64, 256, 0, stream>>>(b1, W2, b2, b12);

    // phase1: bf16 operands
    k_cvtx<<<4096, 256, 0, stream>>>(emb, pos, xb);
    k_tcq<<<dim3(16, 48), 256, 0, stream>>>(Wq, Wk, Wv, WBt);
    k_tc<<<dim3(16, 16), 256, 0, stream>>>(Wproj, WpT, 1024, 1024, 64, 64 * 1024);

    // fused QKV: Qb bf16 + K fp32/bf16 + V fp32
    k_mm<128, 0, 1><<<dim3(32, 24), 256, 0, stream>>>(xb, WBt, 1024, 1024,
        nullptr, nullptr, nullptr, nullptr, nullptr, QbU, out_K, KbU, out_V, 0);
    // VbT[hb][a][s] bf16 from out_V fp32
    k_tc<<<dim3(32, 32), 256, 0, stream>>>(out_V, VbT, 64, 2048, 131072, 131072);

    // flash attention: attnO bf16 in-place over Qb
    k_flash<<<dim3(32, 32), 256, 0, stream>>>(QbU, KbU, VbT);

    // res1 = attnO @ WprojT^T + emb + pos -> ws
    k_mm<64, 2, 0><<<dim3(64, 8), 256, 0, stream>>>(QbU, WpT, 1024, 1024,
        res1, nullptr, nullptr, emb, pos, nullptr, nullptr, nullptr, nullptr, 0);
    k_ln<<<4096, 256, 0, stream>>>(res1, nullptr, g_attn, be_attn, res1);  // mha in-place

    // res2 = relu(mha @ W12 + b12) + mha -> enc
    k_mm<64, 1, 0><<<dim3(64, 8), 256, 0, stream>>>(res1, W12T, 1024, 1024,
        enc, nullptr, b12, res1, nullptr, nullptr, nullptr, nullptr, nullptr, 1);
    // encoded = LN(mha + LN(res2))
    k_ln23<<<4096, 256, 0, stream>>>(enc, res1, g_ffn, be_ffn, g_out, be_out, enc);
}

// Round 3
// 440.550 us; speedup vs baseline: 2.2305x; 1.1568x over previous
//
#include <hip/hip_runtime.h>

// TransformerEncoder on MI355X (gfx950). fp32 I/O, bf16 MFMA compute.
// B=2, S=2048, E=1024, H=16, A=64, FF=4096. Tokens M = 4096.
//
// ws layout (<= 20MB+4KB):
//   fixed : [16,18M)=WpT bf16, [18,20M)=W12T bf16, [20M,+4K)=b12 f32
//   phase0: [0,8M)=W1b bf16, [8,16M)=W2t bf16 (splitK partials in enc scratch)
//   phase1: [0,6M)=WBt bf16 (Wq|Wk|Wv [n][k]), [8,16M)=xb bf16
//   phase2: [0,8M)=VbT bf16 [hb][a][s]
//   phase3: [0,16M)=res1/mha fp32
// d_out: enc = {Qb bf16[0,8M) -> attnO bf16 in-place | Kb bf16[8,16M)}
//        -> (phase0 splitK scratch, 16MB) -> res2 fp32 -> encoded fp32.

typedef unsigned short u16;
typedef unsigned int u32;
typedef __bf16 bf16x8 __attribute__((ext_vector_type(8)));
typedef float f32x4 __attribute__((ext_vector_type(4)));

#define AS1 __attribute__((address_space(1)))
#define AS3 __attribute__((address_space(3)))

__device__ __forceinline__ u16 f2bf(float f) {
    u32 x = __float_as_uint(f);
    x += 0x7fffu + ((x >> 16) & 1u);
    return (u16)(x >> 16);
}

// XOR swizzle key for a 128B LDS row (flips byte bits 4..6).
__device__ __forceinline__ int swz(int row) { return ((row ^ (row >> 2)) & 7) << 4; }

// async global->LDS, 16B/lane. LDS dest linear; swizzle pre-applied on the
// per-lane GLOBAL source (rule #21: both-sides-or-neither).
__device__ __forceinline__ void gload16(void* lds, const void* g) {
    __builtin_amdgcn_global_load_lds((const AS1 void*)(unsigned long long)g,
                                     (AS3 void*)(u32)(unsigned long long)lds, 16, 0, 0);
}

// ---------------------------------------------------------------- GEMM
// C[m,n] = sum_k A[m,k] * B[n,k]^T.  B bf16 [n][k].
// AMODE 0: A bf16 [m][K] via gload16.  1: A fp32 [m][K] convert-stage.
//       2: A = attnO bf16 head-major (addr = (k>>6)*262144 + m*64 + (k&63)).
// OMODE 0: fp32 out (+bias/relu/resid/resid2), ldc=1024.
//       1: QKV routing (Q->bf16 head-major, K->fp32+bf16, V->fp32).
//       2: fp32 transposed partial Cp[z][n][m]  (splitK for W12T).
template <int BM, int AMODE, int OMODE>
__launch_bounds__(256, 3)
__global__ void k_mm(const void* Ap, const u16* __restrict__ Bt, int K, int KZ,
                     float* C, float* Cp, const float* __restrict__ bias,
                     const float* resid, const float* resid2,
                     u16* oQb, float* oKf, u16* oKb, float* oVf, int relu) {
    constexpr int MF = BM / 32;
    __shared__ __align__(16) u16 As[BM * 64];
    __shared__ __align__(16) u16 Bs[128 * 64];
    const int tid = threadIdx.x;
    const int wave = tid >> 6, lane = tid & 63, quad = lane >> 4, l16 = lane & 15;
    const int wm = wave & 1, wn = wave >> 1;
    const int m0 = blockIdx.x * BM, n0 = blockIdx.y * 128;
    const int kbeg = blockIdx.z * KZ, kend = kbeg + KZ;

    f32x4 acc[MF][4];
#pragma unroll
    for (int mf = 0; mf < MF; ++mf)
#pragma unroll
        for (int nf = 0; nf < 4; ++nf) acc[mf][nf] = (f32x4){0.f, 0.f, 0.f, 0.f};

    for (int kk = kbeg; kk < kend; kk += 64) {
        __syncthreads();
        // ---- stage A [BM][64]
        if constexpr (AMODE == 1) {
            const float* Af = (const float*)Ap;
#pragma unroll
            for (int i = 0; i < BM / 16; ++i) {
                const int slot = tid + i * 256;
                const int row = slot >> 4, c4 = (slot & 15) * 4;
                float4 v = *(const float4*)(Af + (long long)(m0 + row) * K + kk + c4);
                ushort4 s;
                s.x = f2bf(v.x); s.y = f2bf(v.y); s.z = f2bf(v.z); s.w = f2bf(v.w);
                *(ushort4*)((char*)As + row * 128 + ((c4 * 2) ^ swz(row))) = s;
            }
        } else {
            const u16* Ab = (const u16*)Ap;
#pragma unroll
            for (int i = 0; i < BM / 32; ++i) {
                const int chunk = wave * (BM / 32) + i;
                const int row = chunk * 8 + (lane >> 3);
                const int cb = (lane & 7) * 16;
                const int e = kk + ((cb ^ swz(row)) >> 1);
                const u16* src;
                if constexpr (AMODE == 2)
                    src = Ab + (long long)(e >> 6) * 262144 + (long long)(m0 + row) * 64 + (e & 63);
                else
                    src = Ab + (long long)(m0 + row) * K + e;
                gload16((char*)As + chunk * 1024, src);
            }
        }
        // ---- stage B [128][64]
#pragma unroll
        for (int i = 0; i < 4; ++i) {
            const int chunk = wave * 4 + i;
            const int row = chunk * 8 + (lane >> 3);
            const int cb = (lane & 7) * 16;
            gload16((char*)Bs + chunk * 1024,
                    Bt + (long long)(n0 + row) * K + kk + ((cb ^ swz(row)) >> 1));
        }
        __syncthreads();
        // ---- compute
#pragma unroll
        for (int ks = 0; ks < 2; ++ks) {
            bf16x8 af[MF], bfr[4];
#pragma unroll
            for (int mf = 0; mf < MF; ++mf) {
                const int row = wm * (BM / 2) + mf * 16 + l16;
                af[mf] = *(const bf16x8*)((const char*)As + row * 128 +
                                          ((ks * 64 + quad * 16) ^ swz(row)));
            }
#pragma unroll
            for (int nf = 0; nf < 4; ++nf) {
                const int row = wn * 64 + nf * 16 + l16;
                bfr[nf] = *(const bf16x8*)((const char*)Bs + row * 128 +
                                           ((ks * 64 + quad * 16) ^ swz(row)));
            }
#pragma unroll
            for (int mf = 0; mf < MF; ++mf)
#pragma unroll
                for (int nf = 0; nf < 4; ++nf)
                    acc[mf][nf] = __builtin_amdgcn_mfma_f32_16x16x32_bf16(af[mf], bfr[nf],
                                                                          acc[mf][nf], 0, 0, 0);
        }
    }

    // ---- epilogue
#pragma unroll
    for (int mf = 0; mf < MF; ++mf) {
#pragma unroll
        for (int nf = 0; nf < 4; ++nf) {
#pragma unroll
            for (int r = 0; r < 4; ++r) {
                const long long row = m0 + wm * (BM / 2) + mf * 16 + quad * 4 + r;
                const int col = n0 + wn * 64 + nf * 16 + l16;
                float v = acc[mf][nf][r];
                if constexpr (OMODE == 0) {
                    if (bias) v += bias[col];
                    if (relu) v = fmaxf(v, 0.f);
                    if (resid) v += resid[row * 1024 + col];
                    if (resid2) v += resid2[row * 1024 + col];
                    C[row * 1024 + col] = v;
                } else if constexpr (OMODE == 1) {
                    const int sel = col >> 10, h = (col >> 6) & 15, a = col & 63;
                    const long long idx = (long long)h * 262144 + row * 64 + a;
                    if (sel == 0) oQb[idx] = f2bf(v);
                    else if (sel == 1) { oKf[idx] = v; oKb[idx] = f2bf(v); }
                    else oVf[idx] = v;
                } else {
                    Cp[(long long)blockIdx.z * 1048576 + (long long)col * 1024 + row] = v;
                }
            }
        }
    }
}

// ---------------------------------------------------------------- converts
__global__ void k_cvtx(const float* __restrict__ a, const float* __restrict__ b,
                       u16* __restrict__ o) {
    const long long i = ((long long)blockIdx.x * 256 + threadIdx.x) * 4;
    float4 v = *(const float4*)(a + i);
    if (b) {
        float4 u = *(const float4*)(b + i);
        v.x += u.x; v.y += u.y; v.z += u.z; v.w += u.w;
    }
    ushort4 s;
    s.x = f2bf(v.x); s.y = f2bf(v.y); s.z = f2bf(v.z); s.w = f2bf(v.w);
    *(ushort4*)(o + i) = s;
}

// tiled 64x64 transpose-convert (generic): coalesced both sides.
__global__ void k_tc(const float* __restrict__ in, u16* __restrict__ out,
                     long long ldin, long long ldout, long long szin, long long szout) {
    __shared__ float T[64][65];
    const int x = blockIdx.x, z = blockIdx.y, tid = threadIdx.x;
    const float* ip = in + (long long)z * szin + (long long)x * 64 * ldin;
    u16* op = out + (long long)z * szout + (long long)x * 64;
#pragma unroll
    for (int i = 0; i < 4; ++i) {
        const int slot = tid + i * 256;
        const int r = slot >> 4, c4 = (slot & 15) * 4;
        float4 v = *(const float4*)(ip + (long long)r * ldin + c4);
        T[r][c4] = v.x; T[r][c4 + 1] = v.y; T[r][c4 + 2] = v.z; T[r][c4 + 3] = v.w;
    }
    __syncthreads();
#pragma unroll
    for (int i = 0; i < 4; ++i) {
        const int slot = tid + i * 256;
        const int c = slot >> 4, r4 = (slot & 15) * 4;
        ushort4 s;
        s.x = f2bf(T[r4][c]); s.y = f2bf(T[r4 + 1][c]);
        s.z = f2bf(T[r4 + 2][c]); s.w = f2bf(T[r4 + 3][c]);
        *(ushort4*)(op + (long long)c * ldout + r4) = s;
    }
}

// weight transpose: z -> (w = z>>4, h = z&15).
//   w<3 : in W[h][k][a] -> WBt[(w*1024+h*64+a)][k]   (QKV, ldin=64)
//   w==3: in Wproj[k][n] -> WpT[n][k]                 (ldin=1024)
__global__ void k_tcq(const float* __restrict__ Wq, const float* __restrict__ Wk,
                      const float* __restrict__ Wv, const float* __restrict__ Wp,
                      u16* __restrict__ outq, u16* __restrict__ outp) {
    __shared__ float T[64][65];
    const int x = blockIdx.x, z = blockIdx.y, tid = threadIdx.x;
    const int w = z >> 4, h = z & 15;
    const float* ip;
    u16* op;
    long long ldin;
    if (w < 3) {
        ip = (w == 0 ? Wq : (w == 1 ? Wk : Wv)) + h * 65536 + x * 4096;
        op = outq + (long long)(w * 16 + h) * 65536 + x * 64;
        ldin = 64;
    } else {
        ip = Wp + x * 65536 + h * 64;
        op = outp + (long long)h * 65536 + x * 64;
        ldin = 1024;
    }
#pragma unroll
    for (int i = 0; i < 4; ++i) {
        const int slot = tid + i * 256;
        const int r = slot >> 4, c4 = (slot & 15) * 4;
        float4 v = *(const float4*)(ip + (long long)r * ldin + c4);
        T[r][c4] = v.x; T[r][c4 + 1] = v.y; T[r][c4 + 2] = v.z; T[r][c4 + 3] = v.w;
    }
    __syncthreads();
#pragma unroll
    for (int i = 0; i < 4; ++i) {
        const int slot = tid + i * 256;
        const int c = slot >> 4, r4 = (slot & 15) * 4;
        ushort4 s;
        s.x = f2bf(T[r4][c]); s.y = f2bf(T[r4 + 1][c]);
        s.z = f2bf(T[r4 + 2][c]); s.w = f2bf(T[r4 + 3][c]);
        *(ushort4*)(op + (long long)c * 1024 + r4) = s;
    }
}

// splitK reduce (4 partials): W12T = bf16(P0+P1+P2+P3)
__global__ void k_red(const float* __restrict__ P, u16* __restrict__ out) {
    const long long i = ((long long)blockIdx.x * 256 + threadIdx.x) * 4;
    float4 a = *(const float4*)(P + i);
    float4 b = *(const float4*)(P + i + 1048576);
    float4 c = *(const float4*)(P + i + 2097152);
    float4 d = *(const float4*)(P + i + 3145728);
    ushort4 s;
    s.x = f2bf(a.x + b.x + c.x + d.x); s.y = f2bf(a.y + b.y + c.y + d.y);
    s.z = f2bf(a.z + b.z + c.z + d.z); s.w = f2bf(a.w + b.w + c.w + d.w);
    *(ushort4*)(out + i) = s;
}

// ---------------------------------------------------------------- b12 = b1@W2 + b2
__global__ void k_b12(const float* __restrict__ b1, const float* __restrict__ W2,
                      const float* __restrict__ b2, float* __restrict__ b12) {
    __shared__ float red[256];
    const int tid = threadIdx.x;
    const int o = blockIdx.x * 16 + (tid & 15);
    const int fc = tid >> 4;
    float s = 0.f;
    for (int f = fc * 256; f < fc * 256 + 256; ++f) s += b1[f] * W2[(long long)f * 1024 + o];
    red[tid] = s;
    __syncthreads();
    if (tid < 16) {
        float t = 0.f;
#pragma unroll
        for (int c = 0; c < 16; ++c) t += red[c * 16 + tid];
        b12[blockIdx.x * 16 + tid] = t + b2[blockIdx.x * 16 + tid];
    }
}

// ---------------------------------------------------------------- flash attention
// grid (16, H*B), 512 threads. 128 q-rows/block (wave w owns rows w*16..+15),
// KV tiles of 64, double-buffered DMA, ONE barrier/tile.
// SWAPPED QK^T: sc = mfma(K_frag, Q_frag) -> S^T fragment with q = lane&15.
// Each lane owns 16 scores of ONE q-row -> row stats reduce in 2 shuffles
// (xor16,xor32); alpha/l broadcast back to O rows via width-16 shuffles.
// Inputs bf16: Qb/Kb head-major [h][t][64], VbT [hb][a][s]. scale 1/32, causal.
// Output bf16 IN-PLACE over this block's own Q tile.
__launch_bounds__(512, 2)
__global__ void k_flash(u16* Qb, const u16* __restrict__ Kb, const u16* __restrict__ Vg) {
    __shared__ __align__(16) u16 Ks[2][64 * 64];
    __shared__ __align__(16) u16 Vs[2][64 * 64];
    __shared__ __align__(16) u16 Pb[8][16 * 64];   // per-wave [16 q][64 k], 128B rows
    const int tid = threadIdx.x;
    const int wave = tid >> 6, lane = tid & 63, quad = lane >> 4, l16 = lane & 15;
    const int hb = blockIdx.y, h = hb >> 1, b = hb & 1;
    const int xr = 15 - (int)blockIdx.x;           // long blocks launch first
    const int q0 = xr * 128;
    const long long qbase = (long long)h * 262144 + (long long)b * 131072;
    u16* Qp = Qb + qbase + (long long)q0 * 64;
    const u16* Kp = Kb + qbase;
    const u16* Vp = Vg + (long long)hb * 131072;
    const float NEG = -1.0e30f;

    // Q -> registers (wave w rows w*16..+15)
    const int qrow = wave * 16 + l16;
    const bf16x8 aq0 = *(const bf16x8*)(Qp + qrow * 64 + quad * 8);
    const bf16x8 aq1 = *(const bf16x8*)(Qp + qrow * 64 + 32 + quad * 8);

    f32x4 o[4];
#pragma unroll
    for (int g = 0; g < 4; ++g) o[g] = (f32x4){0.f, 0.f, 0.f, 0.f};
    float mrun = NEG, lrun = 0.f;                  // stats for q = q0+wave*16+l16
    u16* Pw = Pb[wave];

    auto stage = [&](int bi, int k0) {
        const int row = tid >> 3;                  // 512 thr: 1 gload16 each for K,V
        const int cb = (tid & 7) * 16;
        const int eo = (cb ^ swz(row)) >> 1;
        gload16((char*)Ks[bi] + tid * 16, Kp + (long long)(k0 + row) * 64 + eo);
        gload16((char*)Vs[bi] + tid * 16, Vp + (long long)row * 2048 + k0 + eo);
    };

    const int nit = 2 * xr + 2;
    stage(0, 0);
    int cur = 0;
    for (int it = 0; it < nit; ++it) {
        __syncthreads();                           // drains vmcnt: buf[cur] ready
        if (it + 1 < nit) stage(cur ^ 1, (it + 1) * 64);
        // S^T[64k][16q]: swapped operands, same registers
        f32x4 sc[4];
        __builtin_amdgcn_s_setprio(1);
#pragma unroll
        for (int kg = 0; kg < 4; ++kg) {
            const int krow = kg * 16 + l16;
            const bf16x8 bka = *(const bf16x8*)((const char*)Ks[cur] + krow * 128 +
                                                ((quad * 16) ^ swz(krow)));
            const bf16x8 bkb = *(const bf16x8*)((const char*)Ks[cur] + krow * 128 +
                                                ((64 + quad * 16) ^ swz(krow)));
            sc[kg] = (f32x4){0.f, 0.f, 0.f, 0.f};
            sc[kg] = __builtin_amdgcn_mfma_f32_16x16x32_bf16(bka, aq0, sc[kg], 0, 0, 0);
            sc[kg] = __builtin_amdgcn_mfma_f32_16x16x32_bf16(bkb, aq1, sc[kg], 0, 0, 0);
        }
        __builtin_amdgcn_s_setprio(0);
        // wave-parallel online softmax: lane owns q = q0+wave*16+l16,
        // its 16 scores are k = k0 + kg*16 + quad*4 + r
        const int k0 = it * 64;
        const int q = q0 + wave * 16 + l16;
        const bool edge = (it >= nit - 2);         // only last 2 tiles cross diagonal
        float vv[4][4];
        float tmax = NEG;
#pragma unroll
        for (int kg = 0; kg < 4; ++kg)
#pragma unroll
            for (int r = 0; r < 4; ++r) {
                float x = sc[kg][r] * 0.03125f;
                if (edge && (k0 + kg * 16 + quad * 4 + r > q)) x = NEG;
                vv[kg][r] = x;
                tmax = fmaxf(tmax, x);
            }
        tmax = fmaxf(tmax, __shfl_xor(tmax, 16));
        tmax = fmaxf(tmax, __shfl_xor(tmax, 32));
        const float mn = fmaxf(mrun, tmax);
        const float alpha = __expf(mrun - mn);
        mrun = mn;
        float rs = 0.f;
#pragma unroll
        for (int kg = 0; kg < 4; ++kg)
#pragma unroll
            for (int r = 0; r < 4; ++r) {
                const float e = __expf(vv[kg][r] - mn);
                vv[kg][r] = e;
                rs += e;
            }
        rs += __shfl_xor(rs, 16);
        rs += __shfl_xor(rs, 32);
        lrun = lrun * alpha + rs;
        // rescale O rows (row r of o = q' = q0+wave*16+quad*4+r; alpha_q' in lane l16=q')
#pragma unroll
        for (int r = 0; r < 4; ++r) {
            const float ar = __shfl(alpha, quad * 4 + r, 16);
#pragma unroll
            for (int g = 0; g < 4; ++g) o[g][r] *= ar;
        }
        // P store: row q=l16, packed quads of k (8B stores), swizzled
#pragma unroll
        for (int kg = 0; kg < 4; ++kg) {
            ushort4 s;
            s.x = f2bf(vv[kg][0]); s.y = f2bf(vv[kg][1]);
            s.z = f2bf(vv[kg][2]); s.w = f2bf(vv[kg][3]);
            *(ushort4*)((char*)Pw + l16 * 128 + ((kg * 32 + quad * 8) ^ swz(l16))) = s;
        }
        const bf16x8 ap0 = *(const bf16x8*)((const char*)Pw + l16 * 128 +
                                            ((quad * 16) ^ swz(l16)));
        const bf16x8 ap1 = *(const bf16x8*)((const char*)Pw + l16 * 128 +
                                            ((64 + quad * 16) ^ swz(l16)));
        __builtin_amdgcn_s_setprio(1);
#pragma unroll
        for (int g = 0; g < 4; ++g) {
            const int ar = g * 16 + l16;
            const bf16x8 bv0 = *(const bf16x8*)((const char*)Vs[cur] + ar * 128 +
                                                ((quad * 16) ^ swz(ar)));
            const bf16x8 bv1 = *(const bf16x8*)((const char*)Vs[cur] + ar * 128 +
                                                ((64 + quad * 16) ^ swz(ar)));
            o[g] = __builtin_amdgcn_mfma_f32_16x16x32_bf16(ap0, bv0, o[g], 0, 0, 0);
            o[g] = __builtin_amdgcn_mfma_f32_16x16x32_bf16(ap1, bv1, o[g], 0, 0, 0);
        }
        __builtin_amdgcn_s_setprio(0);
        cur ^= 1;
    }

    // epilogue: O /= l (broadcast per O-row), bf16 in-place over own Q tile
#pragma unroll
    for (int r = 0; r < 4; ++r) {
        const float lr = __shfl(lrun, quad * 4 + r, 16);
        const float inv = 1.0f / lr;
        const int srow = wave * 16 + quad * 4 + r;
#pragma unroll
        for (int g = 0; g < 4; ++g)
            Qp[srow * 64 + g * 16 + l16] = f2bf(o[g][r] * inv);
    }
}

// ---------------------------------------------------------------- layernorm (row of 1024)
__global__ void k_ln(const float* in1, const float* in2,
                     const float* __restrict__ g, const float* __restrict__ be,
                     float* out) {
    __shared__ float red[8];
    const int m = blockIdx.x, tid = threadIdx.x, e0 = tid * 4;
    const long long bp = (long long)m * 1024;
    float4 v = *(const float4*)(in1 + bp + e0);
    if (in2) {
        float4 u = *(const float4*)(in2 + bp + e0);
        v.x += u.x; v.y += u.y; v.z += u.z; v.w += u.w;
    }
    float s1 = v.x + v.y + v.z + v.w;
    float s2 = v.x * v.x + v.y * v.y + v.z * v.z + v.w * v.w;
#pragma unroll
    for (int off = 1; off < 64; off <<= 1) { s1 += __shfl_xor(s1, off); s2 += __shfl_xor(s2, off); }
    if ((tid & 63) == 0) { red[tid >> 6] = s1; red[4 + (tid >> 6)] = s2; }
    __syncthreads();
    const float S1 = red[0] + red[1] + red[2] + red[3];
    const float S2 = red[4] + red[5] + red[6] + red[7];
    const float mean = S1 * (1.0f / 1024.0f);
    const float var = S2 * (1.0f / 1024.0f) - mean * mean;
    const float rstd = rsqrtf(var + 1e-5f);
    float4 ug = *(const float4*)(g + e0);
    float4 ub = *(const float4*)(be + e0);
    float4 o;
    o.x = (v.x - mean) * rstd * ug.x + ub.x;
    o.y = (v.y - mean) * rstd * ug.y + ub.y;
    o.z = (v.z - mean) * rstd * ug.z + ub.z;
    o.w = (v.w - mean) * rstd * ug.w + ub.w;
    *(float4*)(out + bp + e0) = o;
}

// fused: ffout = LN(res2)*g1+be1 ; out = LN(mha + ffout)*g2+be2
__global__ void k_ln23(const float* r2, const float* __restrict__ mha,
                       const float* __restrict__ g1, const float* __restrict__ be1,
                       const float* __restrict__ g2, const float* __restrict__ be2,
                       float* out) {
    __shared__ float red[8];
    const int m = blockIdx.x, tid = threadIdx.x, e0 = tid * 4;
    const long long bp = (long long)m * 1024;
    float4 v = *(const float4*)(r2 + bp + e0);
    float s1 = v.x + v.y + v.z + v.w;
    float s2 = v.x * v.x + v.y * v.y + v.z * v.z + v.w * v.w;
#pragma unroll
    for (int off = 1; off < 64; off <<= 1) { s1 += __shfl_xor(s1, off); s2 += __shfl_xor(s2, off); }
    if ((tid & 63) == 0) { red[tid >> 6] = s1; red[4 + (tid >> 6)] = s2; }
    __syncthreads();
    float S1 = red[0] + red[1] + red[2] + red[3];
    float S2 = red[4] + red[5] + red[6] + red[7];
    float mean = S1 * (1.0f / 1024.0f);
    float rstd = rsqrtf(S2 * (1.0f / 1024.0f) - mean * mean + 1e-5f);
    float4 ug = *(const float4*)(g1 + e0);
    float4 ub = *(const float4*)(be1 + e0);
    float4 vm = *(const float4*)(mha + bp + e0);
    float4 t;
    t.x = vm.x + (v.x - mean) * rstd * ug.x + ub.x;
    t.y = vm.y + (v.y - mean) * rstd * ug.y + ub.y;
    t.z = vm.z + (v.z - mean) * rstd * ug.z + ub.z;
    t.w = vm.w + (v.w - mean) * rstd * ug.w + ub.w;
    s1 = t.x + t.y + t.z + t.w;
    s2 = t.x * t.x + t.y * t.y + t.z * t.z + t.w * t.w;
#pragma unroll
    for (int off = 1; off < 64; off <<= 1) { s1 += __shfl_xor(s1, off); s2 += __shfl_xor(s2, off); }
    __syncthreads();
    if ((tid & 63) == 0) { red[tid >> 6] = s1; red[4 + (tid >> 6)] = s2; }
    __syncthreads();
    S1 = red[0] + red[1] + red[2] + red[3];
    S2 = red[4] + red[5] + red[6] + red[7];
    mean = S1 * (1.0f / 1024.0f);
    rstd = rsqrtf(S2 * (1.0f / 1024.0f) - mean * mean + 1e-5f);
    ug = *(const float4*)(g2 + e0);
    ub = *(const float4*)(be2 + e0);
    float4 oo;
    oo.x = (t.x - mean) * rstd * ug.x + ub.x;
    oo.y = (t.y - mean) * rstd * ug.y + ub.y;
    oo.z = (t.z - mean) * rstd * ug.z + ub.z;
    oo.w = (t.w - mean) * rstd * ug.w + ub.w;
    *(float4*)(out + bp + e0) = oo;
}

// ---------------------------------------------------------------- launch
extern "C" void kernel_launch(void* const* d_in, const int* in_sizes, int n_in,
                              void* d_out, int out_size, void* d_ws, size_t ws_size,
                              hipStream_t stream) {
    (void)in_sizes; (void)n_in; (void)out_size; (void)ws_size;
    const float* emb    = (const float*)d_in[0];
    const float* pos    = (const float*)d_in[1];
    const float* Wq     = (const float*)d_in[2];
    const float* Wk     = (const float*)d_in[3];
    const float* Wv     = (const float*)d_in[4];
    const float* Wproj  = (const float*)d_in[5];
    const float* W1     = (const float*)d_in[6];
    const float* b1     = (const float*)d_in[7];
    const float* W2     = (const float*)d_in[8];
    const float* b2     = (const float*)d_in[9];
    const float* g_attn = (const float*)d_in[10];
    const float* be_attn= (const float*)d_in[11];
    const float* g_ffn  = (const float*)d_in[12];
    const float* be_ffn = (const float*)d_in[13];
    const float* g_out  = (const float*)d_in[14];
    const float* be_out = (const float*)d_in[15];

    float* enc   = (float*)d_out;
    float* out_K = enc + 4194304;
    float* out_V = enc + 8388608;
    u16* QbU = (u16*)enc;                  // [0,8M) of enc: Qb -> attnO
    u16* KbU = (u16*)enc + 4194304;        // [8,16M) of enc: Kb

    u16* wsu    = (u16*)d_ws;
    u16* W1b    = wsu;                     // [0,8M)   phase0
    u16* W2t    = wsu + 4194304;           // [8,16M)  phase0
    u16* WBt    = wsu;                     // [0,6M)   phase1
    u16* xb     = wsu + 4194304;           // [8,16M)  phase1
    u16* VbT    = wsu;                     // [0,8M)   phase2
    u16* WpT    = wsu + 8388608;           // [16,18M)
    u16* W12T   = wsu + 9437184;           // [18,20M)
    float* b12  = (float*)(wsu + 10485760);// [20M,+4K)
    float* res1 = (float*)d_ws;            // [0,16M)  phase3 (mha after LN)

    // phase0: W12T = (W1@W2)^T bf16, splitK x4 (partials in enc scratch, 16MB)
    k_cvtx<<<4096, 256, 0, stream>>>(W1, nullptr, W1b);
    k_tc<<<dim3(64, 16), 256, 0, stream>>>(W2, W2t, 1024, 4096, 64, 64 * 4096);
    k_mm<64, 0, 2><<<dim3(16, 8, 4), 256, 0, stream>>>(W1b, W2t, 4096, 1024,
        nullptr, enc, nullptr, nullptr, nullptr, nullptr, nullptr, nullptr, nullptr, 0);
    k_red<<<1024, 256, 0, stream>>>(enc, W12T);
    k_b12<<<64, 256, 0, stream>>>(b1, W2, b2, b12);

    // phase1: bf16 operands (QKV weights + Wproj in one transpose launch)
    k_cvtx<<<4096, 256, 0, stream>>>(emb, pos, xb);
    k_tcq<<<dim3(16, 64), 256, 0, stream>>>(Wq, Wk, Wv, Wproj, WBt, WpT);

    // fused QKV: Qb bf16 + K fp32/bf16 + V fp32
    k_mm<128, 0, 1><<<dim3(32, 24), 256, 0, stream>>>(xb, WBt, 1024, 1024,
        nullptr, nullptr, nullptr, nullptr, nullptr, QbU, out_K, KbU, out_V, 0);
    // VbT[hb][a][s] bf16 from out_V fp32
    k_tc<<<dim3(32, 32), 256, 0, stream>>>(out_V, VbT, 64, 2048, 131072, 131072);

    // flash attention: attnO bf16 in-place over Qb
    k_flash<<<dim3(16, 32), 512, 0, stream>>>(QbU, KbU, VbT);

    // res1 = attnO @ WprojT^T + emb + pos -> ws
    k_mm<64, 2, 0><<<dim3(64, 8), 256, 0, stream>>>(QbU, WpT, 1024, 1024,
        res1, nullptr, nullptr, emb, pos, nullptr, nullptr, nullptr, nullptr, 0);
    k_ln<<<4096, 256, 0, stream>>>(res1, nullptr, g_attn, be_attn, res1);  // mha in-place

    // res2 = relu(mha @ W12 + b12) + mha -> enc
    k_mm<64, 1, 0><<<dim3(64, 8), 256, 0, stream>>>(res1, W12T, 1024, 1024,
        enc, nullptr, b12, res1, nullptr, nullptr, nullptr, nullptr, nullptr, 1);
    // encoded = LN(mha + LN(res2))
    k_ln23<<<4096, 256, 0, stream>>>(enc, res1, g_ffn, be_ffn, g_out, be_out, enc);
}

// Round 4
// 387.541 us; speedup vs baseline: 2.5355x; 1.1368x over previous
//
#include <hip/hip_runtime.h>

// TransformerEncoder on MI355X (gfx950). fp32 I/O, bf16 MFMA compute.
// B=2, S=2048, E=1024, H=16, A=64, FF=4096. Tokens M = 4096.
//
// Memory choreography (launch order; ws = 20MB+4KB, d_out = 48MB):
//   #1 k_prep : W1b bf16 -> enc[0,8M), W2t bf16 -> enc[8,16M),
//               xb bf16 -> ws[8,16M), WBt bf16 -> ws[0,6M),
//               WpT -> ws[16,18M), b12 init=b2 -> ws+20M
//   #2 W12 GEMM splitK x4 : partials fp32 -> out_K slot [16,32M) of d_out
//   #3 k_rb   : W12T bf16 -> ws[18,20M) ; b12 += b1@W2 (atomic)
//   #4 QKV GEMM: Qb bf16 -> enc[0,8M), Kb bf16 -> enc[8,16M),
//               K fp32 -> out_K, V fp32 -> out_V
//   #5 k_tc   : VbT bf16 [hb][a][s] -> ws[0,8M)
//   #6 flash  : attnO bf16 in-place over Qb (enc[0,8M))
//   #7 proj GEMM: res1 fp32 -> ws[0,16M)  (+emb+pos resid)
//   #8 k_ln   : mha = LN(res1) in-place (ws)
//   #9 FFN GEMM: res2 = relu(mha@W12+b12)+mha -> enc[0,16M)
//  #10 k_ln23 : encoded = LN(mha + LN(res2)) -> enc

typedef unsigned short u16;
typedef unsigned int u32;
typedef __bf16 bf16x8 __attribute__((ext_vector_type(8)));
typedef float f32x4 __attribute__((ext_vector_type(4)));

#define AS1 __attribute__((address_space(1)))
#define AS3 __attribute__((address_space(3)))

__device__ __forceinline__ u16 f2bf(float f) {
    u32 x = __float_as_uint(f);
    x += 0x7fffu + ((x >> 16) & 1u);
    return (u16)(x >> 16);
}

// XOR swizzle key for a 128B LDS row (flips byte bits 4..6).
__device__ __forceinline__ int swz(int row) { return ((row ^ (row >> 2)) & 7) << 4; }

// async global->LDS, 16B/lane. LDS dest linear; swizzle pre-applied on the
// per-lane GLOBAL source (rule #21: both-sides-or-neither).
__device__ __forceinline__ void gload16(void* lds, const void* g) {
    __builtin_amdgcn_global_load_lds((const AS1 void*)(unsigned long long)g,
                                     (AS3 void*)(u32)(unsigned long long)lds, 16, 0, 0);
}

// ---------------------------------------------------------------- GEMM
// C[m,n] = sum_k A[m,k] * B[n,k]^T.  B bf16 [n][k].
// AMODE 0: A bf16 [m][K] via gload16.  1: A fp32 [m][K] convert-stage.
//       2: A = attnO bf16 head-major (addr = (k>>6)*262144 + m*64 + (k&63)).
// OMODE 0: fp32 out (+bias/relu/resid/resid2), ldc=1024.
//       1: QKV routing (Q->bf16 head-major, K->fp32+bf16, V->fp32).
//       2: fp32 transposed partial Cp[z][n][m]  (splitK for W12T).
template <int BM, int AMODE, int OMODE>
__launch_bounds__(256, 3)
__global__ void k_mm(const void* Ap, const u16* __restrict__ Bt, int K, int KZ,
                     float* C, float* Cp, const float* __restrict__ bias,
                     const float* resid, const float* resid2,
                     u16* oQb, float* oKf, u16* oKb, float* oVf, int relu) {
    constexpr int MF = BM / 32;
    __shared__ __align__(16) u16 As[BM * 64];
    __shared__ __align__(16) u16 Bs[128 * 64];
    const int tid = threadIdx.x;
    const int wave = tid >> 6, lane = tid & 63, quad = lane >> 4, l16 = lane & 15;
    const int wm = wave & 1, wn = wave >> 1;
    const int m0 = blockIdx.x * BM, n0 = blockIdx.y * 128;
    const int kbeg = blockIdx.z * KZ, kend = kbeg + KZ;

    f32x4 acc[MF][4];
#pragma unroll
    for (int mf = 0; mf < MF; ++mf)
#pragma unroll
        for (int nf = 0; nf < 4; ++nf) acc[mf][nf] = (f32x4){0.f, 0.f, 0.f, 0.f};

    for (int kk = kbeg; kk < kend; kk += 64) {
        __syncthreads();
        // ---- stage A [BM][64]
        if constexpr (AMODE == 1) {
            const float* Af = (const float*)Ap;
#pragma unroll
            for (int i = 0; i < BM / 16; ++i) {
                const int slot = tid + i * 256;
                const int row = slot >> 4, c4 = (slot & 15) * 4;
                float4 v = *(const float4*)(Af + (long long)(m0 + row) * K + kk + c4);
                ushort4 s;
                s.x = f2bf(v.x); s.y = f2bf(v.y); s.z = f2bf(v.z); s.w = f2bf(v.w);
                *(ushort4*)((char*)As + row * 128 + ((c4 * 2) ^ swz(row))) = s;
            }
        } else {
            const u16* Ab = (const u16*)Ap;
#pragma unroll
            for (int i = 0; i < BM / 32; ++i) {
                const int chunk = wave * (BM / 32) + i;
                const int row = chunk * 8 + (lane >> 3);
                const int cb = (lane & 7) * 16;
                const int e = kk + ((cb ^ swz(row)) >> 1);
                const u16* src;
                if constexpr (AMODE == 2)
                    src = Ab + (long long)(e >> 6) * 262144 + (long long)(m0 + row) * 64 + (e & 63);
                else
                    src = Ab + (long long)(m0 + row) * K + e;
                gload16((char*)As + chunk * 1024, src);
            }
        }
        // ---- stage B [128][64]
#pragma unroll
        for (int i = 0; i < 4; ++i) {
            const int chunk = wave * 4 + i;
            const int row = chunk * 8 + (lane >> 3);
            const int cb = (lane & 7) * 16;
            gload16((char*)Bs + chunk * 1024,
                    Bt + (long long)(n0 + row) * K + kk + ((cb ^ swz(row)) >> 1));
        }
        __syncthreads();
        // ---- compute
#pragma unroll
        for (int ks = 0; ks < 2; ++ks) {
            bf16x8 af[MF], bfr[4];
#pragma unroll
            for (int mf = 0; mf < MF; ++mf) {
                const int row = wm * (BM / 2) + mf * 16 + l16;
                af[mf] = *(const bf16x8*)((const char*)As + row * 128 +
                                          ((ks * 64 + quad * 16) ^ swz(row)));
            }
#pragma unroll
            for (int nf = 0; nf < 4; ++nf) {
                const int row = wn * 64 + nf * 16 + l16;
                bfr[nf] = *(const bf16x8*)((const char*)Bs + row * 128 +
                                           ((ks * 64 + quad * 16) ^ swz(row)));
            }
#pragma unroll
            for (int mf = 0; mf < MF; ++mf)
#pragma unroll
                for (int nf = 0; nf < 4; ++nf)
                    acc[mf][nf] = __builtin_amdgcn_mfma_f32_16x16x32_bf16(af[mf], bfr[nf],
                                                                          acc[mf][nf], 0, 0, 0);
        }
    }

    // ---- epilogue
#pragma unroll
    for (int mf = 0; mf < MF; ++mf) {
#pragma unroll
        for (int nf = 0; nf < 4; ++nf) {
#pragma unroll
            for (int r = 0; r < 4; ++r) {
                const long long row = m0 + wm * (BM / 2) + mf * 16 + quad * 4 + r;
                const int col = n0 + wn * 64 + nf * 16 + l16;
                float v = acc[mf][nf][r];
                if constexpr (OMODE == 0) {
                    if (bias) v += bias[col];
                    if (relu) v = fmaxf(v, 0.f);
                    if (resid) v += resid[row * 1024 + col];
                    if (resid2) v += resid2[row * 1024 + col];
                    C[row * 1024 + col] = v;
                } else if constexpr (OMODE == 1) {
                    const int sel = col >> 10, h = (col >> 6) & 15, a = col & 63;
                    const long long idx = (long long)h * 262144 + row * 64 + a;
                    if (sel == 0) oQb[idx] = f2bf(v);
                    else if (sel == 1) { oKf[idx] = v; oKb[idx] = f2bf(v); }
                    else oVf[idx] = v;
                } else {
                    Cp[(long long)blockIdx.z * 1048576 + (long long)col * 1024 + row] = v;
                }
            }
        }
    }
}

// ---------------------------------------------------------------- prep (one launch)
// blocks [0,4096): xb = bf16(emb+pos)        [4096,8192): W1b = bf16(W1)
// blocks [8192,9216): W2t = bf16(W2^T)       [9216,10240): WBt/WpT transposes
// block 10240: b12 = b2
__global__ void k_prep(const float* __restrict__ emb, const float* __restrict__ pos,
                       const float* __restrict__ W1, const float* __restrict__ W2,
                       const float* __restrict__ Wq, const float* __restrict__ Wk,
                       const float* __restrict__ Wv, const float* __restrict__ Wp,
                       const float* __restrict__ b2,
                       u16* __restrict__ xb, u16* __restrict__ W1b,
                       u16* __restrict__ W2t, u16* __restrict__ WBt,
                       u16* __restrict__ WpT, float* __restrict__ b12) {
    __shared__ float T[64][65];
    const int bx = blockIdx.x, tid = threadIdx.x;
    if (bx < 8192) {
        const long long i = ((long long)(bx & 4095) * 256 + tid) * 4;
        const float* a = (bx < 4096) ? emb : W1;
        u16* o = (bx < 4096) ? xb : W1b;
        float4 v = *(const float4*)(a + i);
        if (bx < 4096) {
            float4 u = *(const float4*)(pos + i);
            v.x += u.x; v.y += u.y; v.z += u.z; v.w += u.w;
        }
        ushort4 s;
        s.x = f2bf(v.x); s.y = f2bf(v.y); s.z = f2bf(v.z); s.w = f2bf(v.w);
        *(ushort4*)(o + i) = s;
        return;
    }
    if (bx == 10240) {
        float4 v = *(const float4*)(b2 + tid * 4);
        *(float4*)(b12 + tid * 4) = v;
        return;
    }
    // 64x64 tile transpose-convert
    const float* ip;
    u16* op;
    long long ldin, ldout;
    if (bx < 9216) {                       // W2 [4096][1024] -> W2t [1024][4096]
        const int t = bx - 8192, x = t & 63, z = t >> 6;
        ip = W2 + (long long)z * 64 + (long long)x * 65536;
        ldin = 1024;
        op = W2t + (long long)z * 262144 + x * 64;
        ldout = 4096;
    } else {                               // QKV weights + Wproj -> [n][k]
        const int t = bx - 9216, x = t & 15, z = t >> 4;
        const int w = z >> 4, h = z & 15;
        if (w < 3) {
            ip = (w == 0 ? Wq : (w == 1 ? Wk : Wv)) + h * 65536 + x * 4096;
            ldin = 64;
            op = WBt + (long long)(w * 16 + h) * 65536 + x * 64;
        } else {
            ip = Wp + x * 65536 + h * 64;
            ldin = 1024;
            op = WpT + (long long)h * 65536 + x * 64;
        }
        ldout = 1024;
    }
#pragma unroll
    for (int i = 0; i < 4; ++i) {
        const int slot = tid + i * 256;
        const int r = slot >> 4, c4 = (slot & 15) * 4;
        float4 v = *(const float4*)(ip + (long long)r * ldin + c4);
        T[r][c4] = v.x; T[r][c4 + 1] = v.y; T[r][c4 + 2] = v.z; T[r][c4 + 3] = v.w;
    }
    __syncthreads();
#pragma unroll
    for (int i = 0; i < 4; ++i) {
        const int slot = tid + i * 256;
        const int c = slot >> 4, r4 = (slot & 15) * 4;
        ushort4 s;
        s.x = f2bf(T[r4][c]); s.y = f2bf(T[r4 + 1][c]);
        s.z = f2bf(T[r4 + 2][c]); s.w = f2bf(T[r4 + 3][c]);
        *(ushort4*)(op + (long long)c * ldout + r4) = s;
    }
}

// tiled 64x64 transpose-convert (V -> VbT)
__global__ void k_tc(const float* __restrict__ in, u16* __restrict__ out,
                     long long ldin, long long ldout, long long szin, long long szout) {
    __shared__ float T[64][65];
    const int x = blockIdx.x, z = blockIdx.y, tid = threadIdx.x;
    const float* ip = in + (long long)z * szin + (long long)x * 64 * ldin;
    u16* op = out + (long long)z * szout + (long long)x * 64;
#pragma unroll
    for (int i = 0; i < 4; ++i) {
        const int slot = tid + i * 256;
        const int r = slot >> 4, c4 = (slot & 15) * 4;
        float4 v = *(const float4*)(ip + (long long)r * ldin + c4);
        T[r][c4] = v.x; T[r][c4 + 1] = v.y; T[r][c4 + 2] = v.z; T[r][c4 + 3] = v.w;
    }
    __syncthreads();
#pragma unroll
    for (int i = 0; i < 4; ++i) {
        const int slot = tid + i * 256;
        const int c = slot >> 4, r4 = (slot & 15) * 4;
        ushort4 s;
        s.x = f2bf(T[r4][c]); s.y = f2bf(T[r4 + 1][c]);
        s.z = f2bf(T[r4 + 2][c]); s.w = f2bf(T[r4 + 3][c]);
        *(ushort4*)(op + (long long)c * ldout + r4) = s;
    }
}

// ---------------------------------------------------------------- reduce + b12
// blocks [0,1024): W12T = bf16(P0+P1+P2+P3)
// blocks [1024,1280): b12 += b1@W2 (coalesced full-row reads, atomic accumulate;
//                     b12 pre-initialized to b2 by k_prep)
__global__ void k_rb(const float* __restrict__ P, u16* __restrict__ out,
                     const float* __restrict__ b1, const float* __restrict__ W2,
                     float* __restrict__ b12) {
    const int bx = blockIdx.x, tid = threadIdx.x;
    if (bx < 1024) {
        const long long i = ((long long)bx * 256 + tid) * 4;
        float4 a = *(const float4*)(P + i);
        float4 b = *(const float4*)(P + i + 1048576);
        float4 c = *(const float4*)(P + i + 2097152);
        float4 d = *(const float4*)(P + i + 3145728);
        ushort4 s;
        s.x = f2bf(a.x + b.x + c.x + d.x); s.y = f2bf(a.y + b.y + c.y + d.y);
        s.z = f2bf(a.z + b.z + c.z + d.z); s.w = f2bf(a.w + b.w + c.w + d.w);
        *(ushort4*)(out + i) = s;
    } else {
        const int z = bx - 1024;           // 256 blocks x 16 f-rows
        const int o4 = tid * 4;
        const float* Wr = W2 + (long long)z * 16384 + o4;
        float ax = 0.f, ay = 0.f, az = 0.f, aw = 0.f;
#pragma unroll
        for (int ff = 0; ff < 16; ++ff) {
            const float bb = b1[z * 16 + ff];
            float4 w = *(const float4*)(Wr + ff * 1024);
            ax += bb * w.x; ay += bb * w.y; az += bb * w.z; aw += bb * w.w;
        }
        atomicAdd(b12 + o4, ax);
        atomicAdd(b12 + o4 + 1, ay);
        atomicAdd(b12 + o4 + 2, az);
        atomicAdd(b12 + o4 + 3, aw);
    }
}

// ---------------------------------------------------------------- flash attention
// grid (16, H*B), 512 threads. 128 q-rows/block, KV tiles of 64, double-buffered
// DMA, ONE barrier/tile. Swapped QK^T (q = lane&15) -> 2-shuffle row stats.
// Defer-max (T13, THR=8): skip O-rescale when tile max doesn't grow.
// Output bf16 IN-PLACE over this block's own Q tile.
__launch_bounds__(512, 2)
__global__ void k_flash(u16* Qb, const u16* __restrict__ Kb, const u16* __restrict__ Vg) {
    __shared__ __align__(16) u16 Ks[2][64 * 64];
    __shared__ __align__(16) u16 Vs[2][64 * 64];
    __shared__ __align__(16) u16 Pb[8][16 * 64];
    const int tid = threadIdx.x;
    const int wave = tid >> 6, lane = tid & 63, quad = lane >> 4, l16 = lane & 15;
    const int hb = blockIdx.y, h = hb >> 1, b = hb & 1;
    const int xr = 15 - (int)blockIdx.x;           // long blocks launch first
    const int q0 = xr * 128;
    const long long qbase = (long long)h * 262144 + (long long)b * 131072;
    u16* Qp = Qb + qbase + (long long)q0 * 64;
    const u16* Kp = Kb + qbase;
    const u16* Vp = Vg + (long long)hb * 131072;
    const float NEG = -1.0e30f;

    const int qrow = wave * 16 + l16;
    const bf16x8 aq0 = *(const bf16x8*)(Qp + qrow * 64 + quad * 8);
    const bf16x8 aq1 = *(const bf16x8*)(Qp + qrow * 64 + 32 + quad * 8);

    f32x4 o[4];
#pragma unroll
    for (int g = 0; g < 4; ++g) o[g] = (f32x4){0.f, 0.f, 0.f, 0.f};
    float mrun = NEG, lrun = 0.f;
    u16* Pw = Pb[wave];

    auto stage = [&](int bi, int k0) {
        const int row = tid >> 3;
        const int cb = (tid & 7) * 16;
        const int eo = (cb ^ swz(row)) >> 1;
        gload16((char*)Ks[bi] + tid * 16, Kp + (long long)(k0 + row) * 64 + eo);
        gload16((char*)Vs[bi] + tid * 16, Vp + (long long)row * 2048 + k0 + eo);
    };

    const int nit = 2 * xr + 2;
    stage(0, 0);
    int cur = 0;
    for (int it = 0; it < nit; ++it) {
        __syncthreads();
        if (it + 1 < nit) stage(cur ^ 1, (it + 1) * 64);
        f32x4 sc[4];
        __builtin_amdgcn_s_setprio(1);
#pragma unroll
        for (int kg = 0; kg < 4; ++kg) {
            const int krow = kg * 16 + l16;
            const bf16x8 bka = *(const bf16x8*)((const char*)Ks[cur] + krow * 128 +
                                                ((quad * 16) ^ swz(krow)));
            const bf16x8 bkb = *(const bf16x8*)((const char*)Ks[cur] + krow * 128 +
                                                ((64 + quad * 16) ^ swz(krow)));
            sc[kg] = (f32x4){0.f, 0.f, 0.f, 0.f};
            sc[kg] = __builtin_amdgcn_mfma_f32_16x16x32_bf16(bka, aq0, sc[kg], 0, 0, 0);
            sc[kg] = __builtin_amdgcn_mfma_f32_16x16x32_bf16(bkb, aq1, sc[kg], 0, 0, 0);
        }
        __builtin_amdgcn_s_setprio(0);
        const int k0 = it * 64;
        const int q = q0 + wave * 16 + l16;
        const bool edge = (it >= nit - 2);
        float vv[4][4];
        float tmax = NEG;
#pragma unroll
        for (int kg = 0; kg < 4; ++kg)
#pragma unroll
            for (int r = 0; r < 4; ++r) {
                float x = sc[kg][r] * 0.03125f;
                if (edge && (k0 + kg * 16 + quad * 4 + r > q)) x = NEG;
                vv[kg][r] = x;
                tmax = fmaxf(tmax, x);
            }
        tmax = fmaxf(tmax, __shfl_xor(tmax, 16));
        tmax = fmaxf(tmax, __shfl_xor(tmax, 32));
        if (__all(tmax - mrun <= 8.f)) {
            // defer: keep mrun, no O-rescale; P bounded by e^8
            float rs = 0.f;
#pragma unroll
            for (int kg = 0; kg < 4; ++kg)
#pragma unroll
                for (int r = 0; r < 4; ++r) {
                    const float e = __expf(vv[kg][r] - mrun);
                    vv[kg][r] = e;
                    rs += e;
                }
            rs += __shfl_xor(rs, 16);
            rs += __shfl_xor(rs, 32);
            lrun += rs;
        } else {
            const float mn = fmaxf(mrun, tmax);
            const float alpha = __expf(mrun - mn);
            mrun = mn;
            float rs = 0.f;
#pragma unroll
            for (int kg = 0; kg < 4; ++kg)
#pragma unroll
                for (int r = 0; r < 4; ++r) {
                    const float e = __expf(vv[kg][r] - mn);
                    vv[kg][r] = e;
                    rs += e;
                }
            rs += __shfl_xor(rs, 16);
            rs += __shfl_xor(rs, 32);
            lrun = lrun * alpha + rs;
#pragma unroll
            for (int r = 0; r < 4; ++r) {
                const float ar = __shfl(alpha, quad * 4 + r, 16);
#pragma unroll
                for (int g = 0; g < 4; ++g) o[g][r] *= ar;
            }
        }
        // P (S^T C-layout) -> per-wave LDS (no barrier), read back as A-frag
#pragma unroll
        for (int kg = 0; kg < 4; ++kg) {
            ushort4 s;
            s.x = f2bf(vv[kg][0]); s.y = f2bf(vv[kg][1]);
            s.z = f2bf(vv[kg][2]); s.w = f2bf(vv[kg][3]);
            *(ushort4*)((char*)Pw + l16 * 128 + ((kg * 32 + quad * 8) ^ swz(l16))) = s;
        }
        const bf16x8 ap0 = *(const bf16x8*)((const char*)Pw + l16 * 128 +
                                            ((quad * 16) ^ swz(l16)));
        const bf16x8 ap1 = *(const bf16x8*)((const char*)Pw + l16 * 128 +
                                            ((64 + quad * 16) ^ swz(l16)));
        __builtin_amdgcn_s_setprio(1);
#pragma unroll
        for (int g = 0; g < 4; ++g) {
            const int ar = g * 16 + l16;
            const bf16x8 bv0 = *(const bf16x8*)((const char*)Vs[cur] + ar * 128 +
                                                ((quad * 16) ^ swz(ar)));
            const bf16x8 bv1 = *(const bf16x8*)((const char*)Vs[cur] + ar * 128 +
                                                ((64 + quad * 16) ^ swz(ar)));
            o[g] = __builtin_amdgcn_mfma_f32_16x16x32_bf16(ap0, bv0, o[g], 0, 0, 0);
            o[g] = __builtin_amdgcn_mfma_f32_16x16x32_bf16(ap1, bv1, o[g], 0, 0, 0);
        }
        __builtin_amdgcn_s_setprio(0);
        cur ^= 1;
    }

#pragma unroll
    for (int r = 0; r < 4; ++r) {
        const float lr = __shfl(lrun, quad * 4 + r, 16);
        const float inv = 1.0f / lr;
        const int srow = wave * 16 + quad * 4 + r;
#pragma unroll
        for (int g = 0; g < 4; ++g)
            Qp[srow * 64 + g * 16 + l16] = f2bf(o[g][r] * inv);
    }
}

// ---------------------------------------------------------------- layernorm (row of 1024)
__global__ void k_ln(const float* in1, const float* in2,
                     const float* __restrict__ g, const float* __restrict__ be,
                     float* out) {
    __shared__ float red[8];
    const int m = blockIdx.x, tid = threadIdx.x, e0 = tid * 4;
    const long long bp = (long long)m * 1024;
    float4 v = *(const float4*)(in1 + bp + e0);
    if (in2) {
        float4 u = *(const float4*)(in2 + bp + e0);
        v.x += u.x; v.y += u.y; v.z += u.z; v.w += u.w;
    }
    float s1 = v.x + v.y + v.z + v.w;
    float s2 = v.x * v.x + v.y * v.y + v.z * v.z + v.w * v.w;
#pragma unroll
    for (int off = 1; off < 64; off <<= 1) { s1 += __shfl_xor(s1, off); s2 += __shfl_xor(s2, off); }
    if ((tid & 63) == 0) { red[tid >> 6] = s1; red[4 + (tid >> 6)] = s2; }
    __syncthreads();
    const float S1 = red[0] + red[1] + red[2] + red[3];
    const float S2 = red[4] + red[5] + red[6] + red[7];
    const float mean = S1 * (1.0f / 1024.0f);
    const float var = S2 * (1.0f / 1024.0f) - mean * mean;
    const float rstd = rsqrtf(var + 1e-5f);
    float4 ug = *(const float4*)(g + e0);
    float4 ub = *(const float4*)(be + e0);
    float4 o;
    o.x = (v.x - mean) * rstd * ug.x + ub.x;
    o.y = (v.y - mean) * rstd * ug.y + ub.y;
    o.z = (v.z - mean) * rstd * ug.z + ub.z;
    o.w = (v.w - mean) * rstd * ug.w + ub.w;
    *(float4*)(out + bp + e0) = o;
}

// fused: ffout = LN(res2)*g1+be1 ; out = LN(mha + ffout)*g2+be2
__global__ void k_ln23(const float* r2, const float* __restrict__ mha,
                       const float* __restrict__ g1, const float* __restrict__ be1,
                       const float* __restrict__ g2, const float* __restrict__ be2,
                       float* out) {
    __shared__ float red[8];
    const int m = blockIdx.x, tid = threadIdx.x, e0 = tid * 4;
    const long long bp = (long long)m * 1024;
    float4 v = *(const float4*)(r2 + bp + e0);
    float s1 = v.x + v.y + v.z + v.w;
    float s2 = v.x * v.x + v.y * v.y + v.z * v.z + v.w * v.w;
#pragma unroll
    for (int off = 1; off < 64; off <<= 1) { s1 += __shfl_xor(s1, off); s2 += __shfl_xor(s2, off); }
    if ((tid & 63) == 0) { red[tid >> 6] = s1; red[4 + (tid >> 6)] = s2; }
    __syncthreads();
    float S1 = red[0] + red[1] + red[2] + red[3];
    float S2 = red[4] + red[5] + red[6] + red[7];
    float mean = S1 * (1.0f / 1024.0f);
    float rstd = rsqrtf(S2 * (1.0f / 1024.0f) - mean * mean + 1e-5f);
    float4 ug = *(const float4*)(g1 + e0);
    float4 ub = *(const float4*)(be1 + e0);
    float4 vm = *(const float4*)(mha + bp + e0);
    float4 t;
    t.x = vm.x + (v.x - mean) * rstd * ug.x + ub.x;
    t.y = vm.y + (v.y - mean) * rstd * ug.y + ub.y;
    t.z = vm.z + (v.z - mean) * rstd * ug.z + ub.z;
    t.w = vm.w + (v.w - mean) * rstd * ug.w + ub.w;
    s1 = t.x + t.y + t.z + t.w;
    s2 = t.x * t.x + t.y * t.y + t.z * t.z + t.w * t.w;
#pragma unroll
    for (int off = 1; off < 64; off <<= 1) { s1 += __shfl_xor(s1, off); s2 += __shfl_xor(s2, off); }
    __syncthreads();
    if ((tid & 63) == 0) { red[tid >> 6] = s1; red[4 + (tid >> 6)] = s2; }
    __syncthreads();
    S1 = red[0] + red[1] + red[2] + red[3];
    S2 = red[4] + red[5] + red[6] + red[7];
    mean = S1 * (1.0f / 1024.0f);
    rstd = rsqrtf(S2 * (1.0f / 1024.0f) - mean * mean + 1e-5f);
    ug = *(const float4*)(g2 + e0);
    ub = *(const float4*)(be2 + e0);
    float4 oo;
    oo.x = (t.x - mean) * rstd * ug.x + ub.x;
    oo.y = (t.y - mean) * rstd * ug.y + ub.y;
    oo.z = (t.z - mean) * rstd * ug.z + ub.z;
    oo.w = (t.w - mean) * rstd * ug.w + ub.w;
    *(float4*)(out + bp + e0) = oo;
}

// ---------------------------------------------------------------- launch
extern "C" void kernel_launch(void* const* d_in, const int* in_sizes, int n_in,
                              void* d_out, int out_size, void* d_ws, size_t ws_size,
                              hipStream_t stream) {
    (void)in_sizes; (void)n_in; (void)out_size; (void)ws_size;
    const float* emb    = (const float*)d_in[0];
    const float* pos    = (const float*)d_in[1];
    const float* Wq     = (const float*)d_in[2];
    const float* Wk     = (const float*)d_in[3];
    const float* Wv     = (const float*)d_in[4];
    const float* Wproj  = (const float*)d_in[5];
    const float* W1     = (const float*)d_in[6];
    const float* b1     = (const float*)d_in[7];
    const float* W2     = (const float*)d_in[8];
    const float* b2     = (const float*)d_in[9];
    const float* g_attn = (const float*)d_in[10];
    const float* be_attn= (const float*)d_in[11];
    const float* g_ffn  = (const float*)d_in[12];
    const float* be_ffn = (const float*)d_in[13];
    const float* g_out  = (const float*)d_in[14];
    const float* be_out = (const float*)d_in[15];

    float* enc   = (float*)d_out;
    float* out_K = enc + 4194304;
    float* out_V = enc + 8388608;
    u16* QbU  = (u16*)enc;                 // phase: Qb -> attnO (in-place)
    u16* KbU  = (u16*)enc + 4194304;       // Kb bf16
    u16* W1b  = (u16*)enc;                 // phase0 scratch (dead before QKV)
    u16* W2t  = (u16*)enc + 4194304;       // phase0 scratch
    float* Ppart = out_K;                  // phase0 splitK partials (16MB)

    u16* wsu    = (u16*)d_ws;
    u16* WBt    = wsu;                     // [0,6M)
    u16* xb     = wsu + 4194304;           // [8,16M)
    u16* VbT    = wsu;                     // [0,8M) after QKV
    u16* WpT    = wsu + 8388608;           // [16,18M)
    u16* W12T   = wsu + 9437184;           // [18,20M)
    float* b12  = (float*)(wsu + 10485760);// [20M,+4K)
    float* res1 = (float*)d_ws;            // [0,16M) phase3 (mha after LN)

    // #1 all conversions/transposes + b12 init (one launch)
    k_prep<<<10241, 256, 0, stream>>>(emb, pos, W1, W2, Wq, Wk, Wv, Wproj, b2,
                                      xb, W1b, W2t, WBt, WpT, b12);
    // #2 W12 partials = W1@W2 splitK x4 -> out_K scratch
    k_mm<64, 0, 2><<<dim3(16, 8, 4), 256, 0, stream>>>(W1b, W2t, 4096, 1024,
        nullptr, Ppart, nullptr, nullptr, nullptr, nullptr, nullptr, nullptr, nullptr, 0);
    // #3 W12T bf16 + b12 accumulate
    k_rb<<<1280, 256, 0, stream>>>(Ppart, W12T, b1, W2, b12);

    // #4 fused QKV: Qb bf16 + K fp32/bf16 + V fp32
    k_mm<128, 0, 1><<<dim3(32, 24), 256, 0, stream>>>(xb, WBt, 1024, 1024,
        nullptr, nullptr, nullptr, nullptr, nullptr, QbU, out_K, KbU, out_V, 0);
    // #5 VbT[hb][a][s] bf16 from out_V fp32
    k_tc<<<dim3(32, 32), 256, 0, stream>>>(out_V, VbT, 64, 2048, 131072, 131072);

    // #6 flash attention: attnO bf16 in-place over Qb
    k_flash<<<dim3(16, 32), 512, 0, stream>>>(QbU, KbU, VbT);

    // #7 res1 = attnO @ Wproj + emb + pos -> ws
    k_mm<64, 2, 0><<<dim3(64, 8), 256, 0, stream>>>(QbU, WpT, 1024, 1024,
        res1, nullptr, nullptr, emb, pos, nullptr, nullptr, nullptr, nullptr, 0);
    // #8 mha = LN(res1) in-place
    k_ln<<<4096, 256, 0, stream>>>(res1, nullptr, g_attn, be_attn, res1);

    // #9 res2 = relu(mha @ W12 + b12) + mha -> enc
    k_mm<64, 1, 0><<<dim3(64, 8), 256, 0, stream>>>(res1, W12T, 1024, 1024,
        enc, nullptr, b12, res1, nullptr, nullptr, nullptr, nullptr, nullptr, 1);
    // #10 encoded = LN(mha + LN(res2))
    k_ln23<<<4096, 256, 0, stream>>>(enc, res1, g_ffn, be_ffn, g_out, be_out, enc);
}

// Round 5
// 364.713 us; speedup vs baseline: 2.6942x; 1.0626x over previous
//
#include <hip/hip_runtime.h>

// TransformerEncoder on MI355X (gfx950). fp32 I/O, bf16 MFMA compute.
// B=2, S=2048, E=1024, H=16, A=64, FF=4096. Tokens M = 4096.
//
// Memory choreography (launch order; ws = 20MB+4KB, d_out = 48MB):
//   #1 k_prep : W1b bf16 -> enc[0,8M), W2t bf16 -> enc[8,16M),
//               xb bf16 -> ws[8,16M), WBt bf16 -> ws[0,6M),
//               WpT -> ws[16,18M), b12 init=b2 -> ws+20M
//   #2 W12 GEMM splitK x4 : partials fp32 -> out_K slot [16,32M) of d_out
//   #3 k_rb   : W12T bf16 -> ws[18,20M) ; b12 += b1@W2 (atomic)
//   #4 QKV GEMM: Qb bf16 -> enc[0,8M), Kb bf16 -> enc[8,16M),
//               K fp32 -> out_K, V fp32 -> out_V
//   #5 k_tc   : VbT bf16 [hb][a][s] -> ws[0,8M)
//   #6 flash  : attnO bf16 in-place over Qb (enc[0,8M))
//   #7 proj GEMM: res1 fp32 -> ws[0,16M)  (+emb+pos resid)
//   #8 k_ln   : mha = LN(res1) in-place (ws)
//   #9 FFN GEMM: res2 = relu(mha@W12+b12)+mha -> enc[0,16M)
//  #10 k_ln23 : encoded = LN(mha + LN(res2)) -> enc
//
// GEMM K-loop uses the T3-minimum pipeline: double-buffered LDS, prefetch
// STAGE issued before compute, ONE barrier per K-step (vmcnt drained at the
// barrier covers the tile staged during the previous iteration).

typedef unsigned short u16;
typedef unsigned int u32;
typedef __bf16 bf16x8 __attribute__((ext_vector_type(8)));
typedef float f32x4 __attribute__((ext_vector_type(4)));

#define AS1 __attribute__((address_space(1)))
#define AS3 __attribute__((address_space(3)))

__device__ __forceinline__ u16 f2bf(float f) {
    return __builtin_bit_cast(u16, static_cast<__bf16>(f));  // HW RNE cvt
}

// XOR swizzle key for a 128B LDS row (flips byte bits 4..6).
__device__ __forceinline__ int swz(int row) { return ((row ^ (row >> 2)) & 7) << 4; }

// async global->LDS, 16B/lane. LDS dest linear; swizzle pre-applied on the
// per-lane GLOBAL source (rule #21: both-sides-or-neither).
__device__ __forceinline__ void gload16(void* lds, const void* g) {
    __builtin_amdgcn_global_load_lds((const AS1 void*)(unsigned long long)g,
                                     (AS3 void*)(u32)(unsigned long long)lds, 16, 0, 0);
}

// ---------------------------------------------------------------- GEMM
// C[m,n] = sum_k A[m,k] * B[n,k]^T.  B bf16 [n][k].
// AMODE 0: A bf16 [m][K] via gload16.  1: A fp32 [m][K] convert-stage.
//       2: A = attnO bf16 head-major (addr = (k>>6)*262144 + m*64 + (k&63)).
// OMODE 0: fp32 out (+bias/relu/resid/resid2), ldc=1024.
//       1: QKV routing (Q->bf16 head-major, K->fp32+bf16, V->fp32).
//       2: fp32 transposed partial Cp[z][n][m]  (splitK for W12T).
template <int BM, int AMODE, int OMODE>
__launch_bounds__(256, (BM == 128) ? 2 : 3)
__global__ void k_mm(const void* Ap, const u16* __restrict__ Bt, int K, int KZ,
                     float* C, float* Cp, const float* __restrict__ bias,
                     const float* resid, const float* resid2,
                     u16* oQb, float* oKf, u16* oKb, float* oVf, int relu) {
    constexpr int MF = BM / 32;
    __shared__ __align__(16) u16 As[2][BM * 64];
    __shared__ __align__(16) u16 Bs[2][128 * 64];
    const int tid = threadIdx.x;
    const int wave = tid >> 6, lane = tid & 63, quad = lane >> 4, l16 = lane & 15;
    const int wm = wave & 1, wn = wave >> 1;
    const int m0 = blockIdx.x * BM, n0 = blockIdx.y * 128;
    const int kbeg = blockIdx.z * KZ;
    const int nk = KZ / 64;

    f32x4 acc[MF][4];
#pragma unroll
    for (int mf = 0; mf < MF; ++mf)
#pragma unroll
        for (int nf = 0; nf < 4; ++nf) acc[mf][nf] = (f32x4){0.f, 0.f, 0.f, 0.f};

    auto stageA = [&](int b, int kk) {
        if constexpr (AMODE == 1) {
            const float* Af = (const float*)Ap;
#pragma unroll
            for (int i = 0; i < BM / 16; ++i) {
                const int slot = tid + i * 256;
                const int row = slot >> 4, c4 = (slot & 15) * 4;
                float4 v = *(const float4*)(Af + (long long)(m0 + row) * K + kk + c4);
                ushort4 s;
                s.x = f2bf(v.x); s.y = f2bf(v.y); s.z = f2bf(v.z); s.w = f2bf(v.w);
                *(ushort4*)((char*)As[b] + row * 128 + ((c4 * 2) ^ swz(row))) = s;
            }
        } else {
            const u16* Ab = (const u16*)Ap;
#pragma unroll
            for (int i = 0; i < BM / 32; ++i) {
                const int chunk = wave * (BM / 32) + i;
                const int row = chunk * 8 + (lane >> 3);
                const int cb = (lane & 7) * 16;
                const int e = kk + ((cb ^ swz(row)) >> 1);
                const u16* src;
                if constexpr (AMODE == 2)
                    src = Ab + (long long)(e >> 6) * 262144 + (long long)(m0 + row) * 64 + (e & 63);
                else
                    src = Ab + (long long)(m0 + row) * K + e;
                gload16((char*)As[b] + chunk * 1024, src);
            }
        }
    };
    auto stageB = [&](int b, int kk) {
#pragma unroll
        for (int i = 0; i < 4; ++i) {
            const int chunk = wave * 4 + i;
            const int row = chunk * 8 + (lane >> 3);
            const int cb = (lane & 7) * 16;
            gload16((char*)Bs[b] + chunk * 1024,
                    Bt + (long long)(n0 + row) * K + kk + ((cb ^ swz(row)) >> 1));
        }
    };

    stageA(0, kbeg);
    stageB(0, kbeg);
    int cur = 0;
    for (int t = 0; t < nk; ++t) {
        __syncthreads();                       // drains vmcnt: buf[cur] ready,
                                               // buf[cur^1] reads (iter t-1) done
        if (t + 1 < nk) {
            stageA(cur ^ 1, kbeg + (t + 1) * 64);
            stageB(cur ^ 1, kbeg + (t + 1) * 64);
        }
        // ---- compute on buf[cur]
#pragma unroll
        for (int ks = 0; ks < 2; ++ks) {
            bf16x8 af[MF], bfr[4];
#pragma unroll
            for (int mf = 0; mf < MF; ++mf) {
                const int row = wm * (BM / 2) + mf * 16 + l16;
                af[mf] = *(const bf16x8*)((const char*)As[cur] + row * 128 +
                                          ((ks * 64 + quad * 16) ^ swz(row)));
            }
#pragma unroll
            for (int nf = 0; nf < 4; ++nf) {
                const int row = wn * 64 + nf * 16 + l16;
                bfr[nf] = *(const bf16x8*)((const char*)Bs[cur] + row * 128 +
                                           ((ks * 64 + quad * 16) ^ swz(row)));
            }
#pragma unroll
            for (int mf = 0; mf < MF; ++mf)
#pragma unroll
                for (int nf = 0; nf < 4; ++nf)
                    acc[mf][nf] = __builtin_amdgcn_mfma_f32_16x16x32_bf16(af[mf], bfr[nf],
                                                                          acc[mf][nf], 0, 0, 0);
        }
        cur ^= 1;
    }

    // ---- epilogue
#pragma unroll
    for (int mf = 0; mf < MF; ++mf) {
#pragma unroll
        for (int nf = 0; nf < 4; ++nf) {
#pragma unroll
            for (int r = 0; r < 4; ++r) {
                const long long row = m0 + wm * (BM / 2) + mf * 16 + quad * 4 + r;
                const int col = n0 + wn * 64 + nf * 16 + l16;
                float v = acc[mf][nf][r];
                if constexpr (OMODE == 0) {
                    if (bias) v += bias[col];
                    if (relu) v = fmaxf(v, 0.f);
                    if (resid) v += resid[row * 1024 + col];
                    if (resid2) v += resid2[row * 1024 + col];
                    C[row * 1024 + col] = v;
                } else if constexpr (OMODE == 1) {
                    const int sel = col >> 10, h = (col >> 6) & 15, a = col & 63;
                    const long long idx = (long long)h * 262144 + row * 64 + a;
                    if (sel == 0) oQb[idx] = f2bf(v);
                    else if (sel == 1) { oKf[idx] = v; oKb[idx] = f2bf(v); }
                    else oVf[idx] = v;
                } else {
                    Cp[(long long)blockIdx.z * 1048576 + (long long)col * 1024 + row] = v;
                }
            }
        }
    }
}

// ---------------------------------------------------------------- prep (one launch)
// blocks [0,4096): xb = bf16(emb+pos)        [4096,8192): W1b = bf16(W1)
// blocks [8192,9216): W2t = bf16(W2^T)       [9216,10240): WBt/WpT transposes
// block 10240: b12 = b2
__global__ void k_prep(const float* __restrict__ emb, const float* __restrict__ pos,
                       const float* __restrict__ W1, const float* __restrict__ W2,
                       const float* __restrict__ Wq, const float* __restrict__ Wk,
                       const float* __restrict__ Wv, const float* __restrict__ Wp,
                       const float* __restrict__ b2,
                       u16* __restrict__ xb, u16* __restrict__ W1b,
                       u16* __restrict__ W2t, u16* __restrict__ WBt,
                       u16* __restrict__ WpT, float* __restrict__ b12) {
    __shared__ float T[64][65];
    const int bx = blockIdx.x, tid = threadIdx.x;
    if (bx < 8192) {
        const long long i = ((long long)(bx & 4095) * 256 + tid) * 4;
        const float* a = (bx < 4096) ? emb : W1;
        u16* o = (bx < 4096) ? xb : W1b;
        float4 v = *(const float4*)(a + i);
        if (bx < 4096) {
            float4 u = *(const float4*)(pos + i);
            v.x += u.x; v.y += u.y; v.z += u.z; v.w += u.w;
        }
        ushort4 s;
        s.x = f2bf(v.x); s.y = f2bf(v.y); s.z = f2bf(v.z); s.w = f2bf(v.w);
        *(ushort4*)(o + i) = s;
        return;
    }
    if (bx == 10240) {
        float4 v = *(const float4*)(b2 + tid * 4);
        *(float4*)(b12 + tid * 4) = v;
        return;
    }
    // 64x64 tile transpose-convert
    const float* ip;
    u16* op;
    long long ldin, ldout;
    if (bx < 9216) {                       // W2 [4096][1024] -> W2t [1024][4096]
        const int t = bx - 8192, x = t & 63, z = t >> 6;
        ip = W2 + (long long)z * 64 + (long long)x * 65536;
        ldin = 1024;
        op = W2t + (long long)z * 262144 + x * 64;
        ldout = 4096;
    } else {                               // QKV weights + Wproj -> [n][k]
        const int t = bx - 9216, x = t & 15, z = t >> 4;
        const int w = z >> 4, h = z & 15;
        if (w < 3) {
            ip = (w == 0 ? Wq : (w == 1 ? Wk : Wv)) + h * 65536 + x * 4096;
            ldin = 64;
            op = WBt + (long long)(w * 16 + h) * 65536 + x * 64;
        } else {
            ip = Wp + x * 65536 + h * 64;
            ldin = 1024;
            op = WpT + (long long)h * 65536 + x * 64;
        }
        ldout = 1024;
    }
#pragma unroll
    for (int i = 0; i < 4; ++i) {
        const int slot = tid + i * 256;
        const int r = slot >> 4, c4 = (slot & 15) * 4;
        float4 v = *(const float4*)(ip + (long long)r * ldin + c4);
        T[r][c4] = v.x; T[r][c4 + 1] = v.y; T[r][c4 + 2] = v.z; T[r][c4 + 3] = v.w;
    }
    __syncthreads();
#pragma unroll
    for (int i = 0; i < 4; ++i) {
        const int slot = tid + i * 256;
        const int c = slot >> 4, r4 = (slot & 15) * 4;
        ushort4 s;
        s.x = f2bf(T[r4][c]); s.y = f2bf(T[r4 + 1][c]);
        s.z = f2bf(T[r4 + 2][c]); s.w = f2bf(T[r4 + 3][c]);
        *(ushort4*)(op + (long long)c * ldout + r4) = s;
    }
}

// tiled 64x64 transpose-convert (V -> VbT)
__global__ void k_tc(const float* __restrict__ in, u16* __restrict__ out,
                     long long ldin, long long ldout, long long szin, long long szout) {
    __shared__ float T[64][65];
    const int x = blockIdx.x, z = blockIdx.y, tid = threadIdx.x;
    const float* ip = in + (long long)z * szin + (long long)x * 64 * ldin;
    u16* op = out + (long long)z * szout + (long long)x * 64;
#pragma unroll
    for (int i = 0; i < 4; ++i) {
        const int slot = tid + i * 256;
        const int r = slot >> 4, c4 = (slot & 15) * 4;
        float4 v = *(const float4*)(ip + (long long)r * ldin + c4);
        T[r][c4] = v.x; T[r][c4 + 1] = v.y; T[r][c4 + 2] = v.z; T[r][c4 + 3] = v.w;
    }
    __syncthreads();
#pragma unroll
    for (int i = 0; i < 4; ++i) {
        const int slot = tid + i * 256;
        const int c = slot >> 4, r4 = (slot & 15) * 4;
        ushort4 s;
        s.x = f2bf(T[r4][c]); s.y = f2bf(T[r4 + 1][c]);
        s.z = f2bf(T[r4 + 2][c]); s.w = f2bf(T[r4 + 3][c]);
        *(ushort4*)(op + (long long)c * ldout + r4) = s;
    }
}

// ---------------------------------------------------------------- reduce + b12
// blocks [0,1024): W12T = bf16(P0+P1+P2+P3)
// blocks [1024,1280): b12 += b1@W2 (coalesced full-row reads, atomic accumulate;
//                     b12 pre-initialized to b2 by k_prep)
__global__ void k_rb(const float* __restrict__ P, u16* __restrict__ out,
                     const float* __restrict__ b1, const float* __restrict__ W2,
                     float* __restrict__ b12) {
    const int bx = blockIdx.x, tid = threadIdx.x;
    if (bx < 1024) {
        const long long i = ((long long)bx * 256 + tid) * 4;
        float4 a = *(const float4*)(P + i);
        float4 b = *(const float4*)(P + i + 1048576);
        float4 c = *(const float4*)(P + i + 2097152);
        float4 d = *(const float4*)(P + i + 3145728);
        ushort4 s;
        s.x = f2bf(a.x + b.x + c.x + d.x); s.y = f2bf(a.y + b.y + c.y + d.y);
        s.z = f2bf(a.z + b.z + c.z + d.z); s.w = f2bf(a.w + b.w + c.w + d.w);
        *(ushort4*)(out + i) = s;
    } else {
        const int z = bx - 1024;           // 256 blocks x 16 f-rows
        const int o4 = tid * 4;
        const float* Wr = W2 + (long long)z * 16384 + o4;
        float ax = 0.f, ay = 0.f, az = 0.f, aw = 0.f;
#pragma unroll
        for (int ff = 0; ff < 16; ++ff) {
            const float bb = b1[z * 16 + ff];
            float4 w = *(const float4*)(Wr + ff * 1024);
            ax += bb * w.x; ay += bb * w.y; az += bb * w.z; aw += bb * w.w;
        }
        atomicAdd(b12 + o4, ax);
        atomicAdd(b12 + o4 + 1, ay);
        atomicAdd(b12 + o4 + 2, az);
        atomicAdd(b12 + o4 + 3, aw);
    }
}

// ---------------------------------------------------------------- flash attention
// grid (16, H*B), 512 threads. 128 q-rows/block, KV tiles of 64, double-buffered
// DMA, ONE barrier/tile. Swapped QK^T (q = lane&15) -> 2-shuffle row stats.
// Defer-max (T13, THR=8): skip O-rescale when tile max doesn't grow.
// Output bf16 IN-PLACE over this block's own Q tile.
__launch_bounds__(512, 2)
__global__ void k_flash(u16* Qb, const u16* __restrict__ Kb, const u16* __restrict__ Vg) {
    __shared__ __align__(16) u16 Ks[2][64 * 64];
    __shared__ __align__(16) u16 Vs[2][64 * 64];
    __shared__ __align__(16) u16 Pb[8][16 * 64];
    const int tid = threadIdx.x;
    const int wave = tid >> 6, lane = tid & 63, quad = lane >> 4, l16 = lane & 15;
    const int hb = blockIdx.y, h = hb >> 1, b = hb & 1;
    const int xr = 15 - (int)blockIdx.x;           // long blocks launch first
    const int q0 = xr * 128;
    const long long qbase = (long long)h * 262144 + (long long)b * 131072;
    u16* Qp = Qb + qbase + (long long)q0 * 64;
    const u16* Kp = Kb + qbase;
    const u16* Vp = Vg + (long long)hb * 131072;
    const float NEG = -1.0e30f;

    const int qrow = wave * 16 + l16;
    const bf16x8 aq0 = *(const bf16x8*)(Qp + qrow * 64 + quad * 8);
    const bf16x8 aq1 = *(const bf16x8*)(Qp + qrow * 64 + 32 + quad * 8);

    f32x4 o[4];
#pragma unroll
    for (int g = 0; g < 4; ++g) o[g] = (f32x4){0.f, 0.f, 0.f, 0.f};
    float mrun = NEG, lrun = 0.f;
    u16* Pw = Pb[wave];

    auto stage = [&](int bi, int k0) {
        const int row = tid >> 3;
        const int cb = (tid & 7) * 16;
        const int eo = (cb ^ swz(row)) >> 1;
        gload16((char*)Ks[bi] + tid * 16, Kp + (long long)(k0 + row) * 64 + eo);
        gload16((char*)Vs[bi] + tid * 16, Vp + (long long)row * 2048 + k0 + eo);
    };

    const int nit = 2 * xr + 2;
    stage(0, 0);
    int cur = 0;
    for (int it = 0; it < nit; ++it) {
        __syncthreads();
        if (it + 1 < nit) stage(cur ^ 1, (it + 1) * 64);
        f32x4 sc[4];
        __builtin_amdgcn_s_setprio(1);
#pragma unroll
        for (int kg = 0; kg < 4; ++kg) {
            const int krow = kg * 16 + l16;
            const bf16x8 bka = *(const bf16x8*)((const char*)Ks[cur] + krow * 128 +
                                                ((quad * 16) ^ swz(krow)));
            const bf16x8 bkb = *(const bf16x8*)((const char*)Ks[cur] + krow * 128 +
                                                ((64 + quad * 16) ^ swz(krow)));
            sc[kg] = (f32x4){0.f, 0.f, 0.f, 0.f};
            sc[kg] = __builtin_amdgcn_mfma_f32_16x16x32_bf16(bka, aq0, sc[kg], 0, 0, 0);
            sc[kg] = __builtin_amdgcn_mfma_f32_16x16x32_bf16(bkb, aq1, sc[kg], 0, 0, 0);
        }
        __builtin_amdgcn_s_setprio(0);
        const int k0 = it * 64;
        const int q = q0 + wave * 16 + l16;
        const bool edge = (it >= nit - 2);
        float vv[4][4];
        float tmax = NEG;
#pragma unroll
        for (int kg = 0; kg < 4; ++kg)
#pragma unroll
            for (int r = 0; r < 4; ++r) {
                float x = sc[kg][r] * 0.03125f;
                if (edge && (k0 + kg * 16 + quad * 4 + r > q)) x = NEG;
                vv[kg][r] = x;
                tmax = fmaxf(tmax, x);
            }
        tmax = fmaxf(tmax, __shfl_xor(tmax, 16));
        tmax = fmaxf(tmax, __shfl_xor(tmax, 32));
        if (__all(tmax - mrun <= 8.f)) {
            // defer: keep mrun, no O-rescale; P bounded by e^8
            float rs = 0.f;
#pragma unroll
            for (int kg = 0; kg < 4; ++kg)
#pragma unroll
                for (int r = 0; r < 4; ++r) {
                    const float e = __expf(vv[kg][r] - mrun);
                    vv[kg][r] = e;
                    rs += e;
                }
            rs += __shfl_xor(rs, 16);
            rs += __shfl_xor(rs, 32);
            lrun += rs;
        } else {
            const float mn = fmaxf(mrun, tmax);
            const float alpha = __expf(mrun - mn);
            mrun = mn;
            float rs = 0.f;
#pragma unroll
            for (int kg = 0; kg < 4; ++kg)
#pragma unroll
                for (int r = 0; r < 4; ++r) {
                    const float e = __expf(vv[kg][r] - mn);
                    vv[kg][r] = e;
                    rs += e;
                }
            rs += __shfl_xor(rs, 16);
            rs += __shfl_xor(rs, 32);
            lrun = lrun * alpha + rs;
#pragma unroll
            for (int r = 0; r < 4; ++r) {
                const float ar = __shfl(alpha, quad * 4 + r, 16);
#pragma unroll
                for (int g = 0; g < 4; ++g) o[g][r] *= ar;
            }
        }
        // P (S^T C-layout) -> per-wave LDS (no barrier), read back as A-frag
#pragma unroll
        for (int kg = 0; kg < 4; ++kg) {
            ushort4 s;
            s.x = f2bf(vv[kg][0]); s.y = f2bf(vv[kg][1]);
            s.z = f2bf(vv[kg][2]); s.w = f2bf(vv[kg][3]);
            *(ushort4*)((char*)Pw + l16 * 128 + ((kg * 32 + quad * 8) ^ swz(l16))) = s;
        }
        const bf16x8 ap0 = *(const bf16x8*)((const char*)Pw + l16 * 128 +
                                            ((quad * 16) ^ swz(l16)));
        const bf16x8 ap1 = *(const bf16x8*)((const char*)Pw + l16 * 128 +
                                            ((64 + quad * 16) ^ swz(l16)));
        __builtin_amdgcn_s_setprio(1);
#pragma unroll
        for (int g = 0; g < 4; ++g) {
            const int ar = g * 16 + l16;
            const bf16x8 bv0 = *(const bf16x8*)((const char*)Vs[cur] + ar * 128 +
                                                ((quad * 16) ^ swz(ar)));
            const bf16x8 bv1 = *(const bf16x8*)((const char*)Vs[cur] + ar * 128 +
                                                ((64 + quad * 16) ^ swz(ar)));
            o[g] = __builtin_amdgcn_mfma_f32_16x16x32_bf16(ap0, bv0, o[g], 0, 0, 0);
            o[g] = __builtin_amdgcn_mfma_f32_16x16x32_bf16(ap1, bv1, o[g], 0, 0, 0);
        }
        __builtin_amdgcn_s_setprio(0);
        cur ^= 1;
    }

#pragma unroll
    for (int r = 0; r < 4; ++r) {
        const float lr = __shfl(lrun, quad * 4 + r, 16);
        const float inv = 1.0f / lr;
        const int srow = wave * 16 + quad * 4 + r;
#pragma unroll
        for (int g = 0; g < 4; ++g)
            Qp[srow * 64 + g * 16 + l16] = f2bf(o[g][r] * inv);
    }
}

// ---------------------------------------------------------------- layernorm (row of 1024)
__global__ void k_ln(const float* in1, const float* in2,
                     const float* __restrict__ g, const float* __restrict__ be,
                     float* out) {
    __shared__ float red[8];
    const int m = blockIdx.x, tid = threadIdx.x, e0 = tid * 4;
    const long long bp = (long long)m * 1024;
    float4 v = *(const float4*)(in1 + bp + e0);
    if (in2) {
        float4 u = *(const float4*)(in2 + bp + e0);
        v.x += u.x; v.y += u.y; v.z += u.z; v.w += u.w;
    }
    float s1 = v.x + v.y + v.z + v.w;
    float s2 = v.x * v.x + v.y * v.y + v.z * v.z + v.w * v.w;
#pragma unroll
    for (int off = 1; off < 64; off <<= 1) { s1 += __shfl_xor(s1, off); s2 += __shfl_xor(s2, off); }
    if ((tid & 63) == 0) { red[tid >> 6] = s1; red[4 + (tid >> 6)] = s2; }
    __syncthreads();
    const float S1 = red[0] + red[1] + red[2] + red[3];
    const float S2 = red[4] + red[5] + red[6] + red[7];
    const float mean = S1 * (1.0f / 1024.0f);
    const float var = S2 * (1.0f / 1024.0f) - mean * mean;
    const float rstd = rsqrtf(var + 1e-5f);
    float4 ug = *(const float4*)(g + e0);
    float4 ub = *(const float4*)(be + e0);
    float4 o;
    o.x = (v.x - mean) * rstd * ug.x + ub.x;
    o.y = (v.y - mean) * rstd * ug.y + ub.y;
    o.z = (v.z - mean) * rstd * ug.z + ub.z;
    o.w = (v.w - mean) * rstd * ug.w + ub.w;
    *(float4*)(out + bp + e0) = o;
}

// fused: ffout = LN(res2)*g1+be1 ; out = LN(mha + ffout)*g2+be2
__global__ void k_ln23(const float* r2, const float* __restrict__ mha,
                       const float* __restrict__ g1, const float* __restrict__ be1,
                       const float* __restrict__ g2, const float* __restrict__ be2,
                       float* out) {
    __shared__ float red[8];
    const int m = blockIdx.x, tid = threadIdx.x, e0 = tid * 4;
    const long long bp = (long long)m * 1024;
    float4 v = *(const float4*)(r2 + bp + e0);
    float s1 = v.x + v.y + v.z + v.w;
    float s2 = v.x * v.x + v.y * v.y + v.z * v.z + v.w * v.w;
#pragma unroll
    for (int off = 1; off < 64; off <<= 1) { s1 += __shfl_xor(s1, off); s2 += __shfl_xor(s2, off); }
    if ((tid & 63) == 0) { red[tid >> 6] = s1; red[4 + (tid >> 6)] = s2; }
    __syncthreads();
    float S1 = red[0] + red[1] + red[2] + red[3];
    float S2 = red[4] + red[5] + red[6] + red[7];
    float mean = S1 * (1.0f / 1024.0f);
    float rstd = rsqrtf(S2 * (1.0f / 1024.0f) - mean * mean + 1e-5f);
    float4 ug = *(const float4*)(g1 + e0);
    float4 ub = *(const float4*)(be1 + e0);
    float4 vm = *(const float4*)(mha + bp + e0);
    float4 t;
    t.x = vm.x + (v.x - mean) * rstd * ug.x + ub.x;
    t.y = vm.y + (v.y - mean) * rstd * ug.y + ub.y;
    t.z = vm.z + (v.z - mean) * rstd * ug.z + ub.z;
    t.w = vm.w + (v.w - mean) * rstd * ug.w + ub.w;
    s1 = t.x + t.y + t.z + t.w;
    s2 = t.x * t.x + t.y * t.y + t.z * t.z + t.w * t.w;
#pragma unroll
    for (int off = 1; off < 64; off <<= 1) { s1 += __shfl_xor(s1, off); s2 += __shfl_xor(s2, off); }
    __syncthreads();
    if ((tid & 63) == 0) { red[tid >> 6] = s1; red[4 + (tid >> 6)] = s2; }
    __syncthreads();
    S1 = red[0] + red[1] + red[2] + red[3];
    S2 = red[4] + red[5] + red[6] + red[7];
    mean = S1 * (1.0f / 1024.0f);
    rstd = rsqrtf(S2 * (1.0f / 1024.0f) - mean * mean + 1e-5f);
    ug = *(const float4*)(g2 + e0);
    ub = *(const float4*)(be2 + e0);
    float4 oo;
    oo.x = (t.x - mean) * rstd * ug.x + ub.x;
    oo.y = (t.y - mean) * rstd * ug.y + ub.y;
    oo.z = (t.z - mean) * rstd * ug.z + ub.z;
    oo.w = (t.w - mean) * rstd * ug.w + ub.w;
    *(float4*)(out + bp + e0) = oo;
}

// ---------------------------------------------------------------- launch
extern "C" void kernel_launch(void* const* d_in, const int* in_sizes, int n_in,
                              void* d_out, int out_size, void* d_ws, size_t ws_size,
                              hipStream_t stream) {
    (void)in_sizes; (void)n_in; (void)out_size; (void)ws_size;
    const float* emb    = (const float*)d_in[0];
    const float* pos    = (const float*)d_in[1];
    const float* Wq     = (const float*)d_in[2];
    const float* Wk     = (const float*)d_in[3];
    const float* Wv     = (const float*)d_in[4];
    const float* Wproj  = (const float*)d_in[5];
    const float* W1     = (const float*)d_in[6];
    const float* b1     = (const float*)d_in[7];
    const float* W2     = (const float*)d_in[8];
    const float* b2     = (const float*)d_in[9];
    const float* g_attn = (const float*)d_in[10];
    const float* be_attn= (const float*)d_in[11];
    const float* g_ffn  = (const float*)d_in[12];
    const float* be_ffn = (const float*)d_in[13];
    const float* g_out  = (const float*)d_in[14];
    const float* be_out = (const float*)d_in[15];

    float* enc   = (float*)d_out;
    float* out_K = enc + 4194304;
    float* out_V = enc + 8388608;
    u16* QbU  = (u16*)enc;                 // phase: Qb -> attnO (in-place)
    u16* KbU  = (u16*)enc + 4194304;       // Kb bf16
    u16* W1b  = (u16*)enc;                 // phase0 scratch (dead before QKV)
    u16* W2t  = (u16*)enc + 4194304;       // phase0 scratch
    float* Ppart = out_K;                  // phase0 splitK partials (16MB)

    u16* wsu    = (u16*)d_ws;
    u16* WBt    = wsu;                     // [0,6M)
    u16* xb     = wsu + 4194304;           // [8,16M)
    u16* VbT    = wsu;                     // [0,8M) after QKV
    u16* WpT    = wsu + 8388608;           // [16,18M)
    u16* W12T   = wsu + 9437184;           // [18,20M)
    float* b12  = (float*)(wsu + 10485760);// [20M,+4K)
    float* res1 = (float*)d_ws;            // [0,16M) phase3 (mha after LN)

    // #1 all conversions/transposes + b12 init (one launch)
    k_prep<<<10241, 256, 0, stream>>>(emb, pos, W1, W2, Wq, Wk, Wv, Wproj, b2,
                                      xb, W1b, W2t, WBt, WpT, b12);
    // #2 W12 partials = W1@W2 splitK x4 -> out_K scratch
    k_mm<64, 0, 2><<<dim3(16, 8, 4), 256, 0, stream>>>(W1b, W2t, 4096, 1024,
        nullptr, Ppart, nullptr, nullptr, nullptr, nullptr, nullptr, nullptr, nullptr, 0);
    // #3 W12T bf16 + b12 accumulate
    k_rb<<<1280, 256, 0, stream>>>(Ppart, W12T, b1, W2, b12);

    // #4 fused QKV: Qb bf16 + K fp32/bf16 + V fp32
    k_mm<128, 0, 1><<<dim3(32, 24), 256, 0, stream>>>(xb, WBt, 1024, 1024,
        nullptr, nullptr, nullptr, nullptr, nullptr, QbU, out_K, KbU, out_V, 0);
    // #5 VbT[hb][a][s] bf16 from out_V fp32
    k_tc<<<dim3(32, 32), 256, 0, stream>>>(out_V, VbT, 64, 2048, 131072, 131072);

    // #6 flash attention: attnO bf16 in-place over Qb
    k_flash<<<dim3(16, 32), 512, 0, stream>>>(QbU, KbU, VbT);

    // #7 res1 = attnO @ Wproj + emb + pos -> ws
    k_mm<64, 2, 0><<<dim3(64, 8), 256, 0, stream>>>(QbU, WpT, 1024, 1024,
        res1, nullptr, nullptr, emb, pos, nullptr, nullptr, nullptr, nullptr, 0);
    // #8 mha = LN(res1) in-place
    k_ln<<<4096, 256, 0, stream>>>(res1, nullptr, g_attn, be_attn, res1);

    // #9 res2 = relu(mha @ W12 + b12) + mha -> enc
    k_mm<64, 1, 0><<<dim3(64, 8), 256, 0, stream>>>(res1, W12T, 1024, 1024,
        enc, nullptr, b12, res1, nullptr, nullptr, nullptr, nullptr, nullptr, 1);
    // #10 encoded = LN(mha + LN(res2))
    k_ln23<<<4096, 256, 0, stream>>>(enc, res1, g_ffn, be_ffn, g_out, be_out, enc);
}